// Round 2
// baseline (1042.402 us; speedup 1.0000x reference)
//
#include <hip/hip_runtime.h>
#include <math.h>

#define NN 50000
#define EE 800000
#define CC 256
#define NS (NN * CC)

typedef __attribute__((ext_vector_type(4))) float f32x4;
typedef __attribute__((ext_vector_type(8))) short bf16x8;
typedef __attribute__((ext_vector_type(4))) unsigned int u32x4;
typedef __attribute__((ext_vector_type(2))) unsigned int u32x2;

__device__ __forceinline__ float bf2f(unsigned int u) {
    union { unsigned int i; float f; } c; c.i = u << 16; return c.f;
}
__device__ __forceinline__ unsigned short f2bf(float f) {
    union { float f; unsigned int i; } c; c.f = f;
    unsigned int u = c.i;
    u += 0x7fffu + ((u >> 16) & 1u);
    return (unsigned short)(u >> 16);
}

__global__ void zero_kernel(int* __restrict__ p, int n) {
    int i = blockIdx.x * 256 + threadIdx.x;
    if (i < n) p[i] = 0;
}

// ---------------------------------------------------------------------------
// Prep: transpose+convert weights to bf16 [n][k]; fold rel_att/rel_msg into
// Wk/Wv (per relation); build bias table.
// WT slots: 0-1 WqT(t), 2-4 WckT(r), 5-7 WcvT(r), 8-9 WaT(t)
// ball slots: 0-1 bq(t), 2-4 folded bk(r), 5-7 folded bv(r)
// ---------------------------------------------------------------------------
__global__ void prep_kernel(const float* __restrict__ Wk, const float* __restrict__ bk,
                            const float* __restrict__ Wq, const float* __restrict__ bq,
                            const float* __restrict__ Wv, const float* __restrict__ bv,
                            const float* __restrict__ Wa,
                            const float* __restrict__ rel_att, const float* __restrict__ rel_msg,
                            unsigned short* __restrict__ WT, float* __restrict__ ball)
{
    int id = blockIdx.x * 256 + threadIdx.x;
    const int ts[3] = {0, 1, 0};  // source node type per relation
    if (id < 2 * 65536) {
        int t = id >> 16, rem = id & 65535;
        int n = rem >> 8, k = rem & 255;
        WT[t * 65536 + n * 256 + k] = f2bf(Wq[t * 65536 + k * 256 + n]);
    } else if (id < 5 * 65536) {
        int id2 = id - 2 * 65536;
        int r = id2 >> 16, rem = id2 & 65535;
        int n = rem >> 8, k = rem & 255;
        int h = n >> 5, j = n & 31;
        const float* wkb = Wk + ts[r] * 65536 + k * 256 + h * 32;
        const float* ab  = rel_att + r * 8192 + h * 1024 + j;
        float s = 0.f;
        #pragma unroll 8
        for (int d = 0; d < 32; ++d) s += wkb[d] * ab[d * 32];
        WT[(2 + r) * 65536 + n * 256 + k] = f2bf(s);
    } else if (id < 8 * 65536) {
        int id2 = id - 5 * 65536;
        int r = id2 >> 16, rem = id2 & 65535;
        int n = rem >> 8, k = rem & 255;
        int h = n >> 5, j = n & 31;
        const float* wvb = Wv + ts[r] * 65536 + k * 256 + h * 32;
        const float* mb  = rel_msg + r * 8192 + h * 1024 + j;
        float s = 0.f;
        #pragma unroll 8
        for (int d = 0; d < 32; ++d) s += wvb[d] * mb[d * 32];
        WT[(5 + r) * 65536 + n * 256 + k] = f2bf(s);
    } else if (id < 10 * 65536) {
        int id2 = id - 8 * 65536;
        int t = id2 >> 16, rem = id2 & 65535;
        int n = rem >> 8, k = rem & 255;
        WT[(8 + t) * 65536 + n * 256 + k] = f2bf(Wa[t * 65536 + k * 256 + n]);
    } else if (id < 10 * 65536 + 2048) {
        int id2 = id - 10 * 65536;
        int z = id2 >> 8, c = id2 & 255;
        float v;
        if (z < 2) {
            v = bq[z * 256 + c];
        } else if (z < 5) {
            int r = z - 2, h = c >> 5, j = c & 31;
            const float* bkb = bk + ts[r] * 256 + h * 32;
            const float* ab  = rel_att + r * 8192 + h * 1024 + j;
            v = 0.f;
            for (int d = 0; d < 32; ++d) v += bkb[d] * ab[d * 32];
        } else {
            int r = z - 5, h = c >> 5, j = c & 31;
            const float* bvb = bv + ts[r] * 256 + h * 32;
            const float* mb  = rel_msg + r * 8192 + h * 1024 + j;
            v = 0.f;
            for (int d = 0; d < 32; ++d) v += bvb[d] * mb[d * 32];
        }
        ball[z * 256 + c] = v;
    }
}

// ---------------------------------------------------------------------------
// CSR build: histogram -> exclusive scan -> scatter (all 3 relations)
// ---------------------------------------------------------------------------
__global__ void hist_kernel(const int* __restrict__ d0, const int* __restrict__ d1,
                            const int* __restrict__ d2, int* __restrict__ counts)
{
    int i = blockIdx.x * 256 + threadIdx.x;
    if (i < EE)            atomicAdd(&counts[d0[i]], 1);
    else if (i < 2 * EE)   atomicAdd(&counts[NN + d1[i - EE]], 1);
    else if (i < 3 * EE)   atomicAdd(&counts[2 * NN + d2[i - 2 * EE]], 1);
}

__global__ __launch_bounds__(1024) void scan_kernel(const int* __restrict__ counts,
                                                    int* __restrict__ offsets,
                                                    int* __restrict__ cur)
{
    int r = blockIdx.x;
    const int* c = counts + r * NN;
    int* off = offsets + r * (NN + 1);
    int* cu  = cur + r * NN;
    int t = threadIdx.x, lane = t & 63, wid = t >> 6;
    __shared__ int wsum[16];
    __shared__ int stot;
    int carry = 0;
    for (int base = 0; base < NN; base += 1024) {
        int i = base + t;
        int x = (i < NN) ? c[i] : 0;
        int v = x;
        #pragma unroll
        for (int ofs = 1; ofs < 64; ofs <<= 1) {
            int y = __shfl_up(v, ofs);
            if (lane >= ofs) v += y;
        }
        if (lane == 63) wsum[wid] = v;
        __syncthreads();
        if (t < 16) {
            int wv = wsum[t];
            #pragma unroll
            for (int ofs = 1; ofs < 16; ofs <<= 1) {
                int y = __shfl_up(wv, ofs);
                if (t >= ofs) wv += y;
            }
            wsum[t] = wv;
            if (t == 15) stot = wv;
        }
        __syncthreads();
        int woff = (wid > 0) ? wsum[wid - 1] : 0;
        int excl = carry + woff + v - x;
        if (i < NN) { off[i] = excl; cu[i] = excl; }
        carry += stot;
        __syncthreads();
    }
    if (t == 0) off[NN] = carry;
}

__global__ void scatter_kernel(const int* __restrict__ s0, const int* __restrict__ d0,
                               const int* __restrict__ s1, const int* __restrict__ d1,
                               const int* __restrict__ s2, const int* __restrict__ d2,
                               int* __restrict__ cur, int* __restrict__ srcS)
{
    int i = blockIdx.x * 256 + threadIdx.x;
    int r, e;
    const int *sp, *dp;
    if (i < EE)          { r = 0; e = i;          sp = s0; dp = d0; }
    else if (i < 2 * EE) { r = 1; e = i - EE;     sp = s1; dp = d1; }
    else if (i < 3 * EE) { r = 2; e = i - 2 * EE; sp = s2; dp = d2; }
    else return;
    int dst = dp[e];
    int pos = atomicAdd(&cur[r * NN + dst], 1);
    srcS[r * EE + pos] = sp[e];
}

// ---------------------------------------------------------------------------
// GEMM: [50000,256] @ [256,256] bf16 MFMA, 128x128 tile, BK=64, 4 waves,
// XOR-swizzled LDS. z selects per-type/per-slot params.
// MODE 0: A is f32 (converted during staging), out bf16 + bias.
// MODE 1: A is bf16, out f32 = (acc+bias)*alpha + h*(1-alpha).
// ---------------------------------------------------------------------------
template<int MODE>
__global__ __launch_bounds__(256, 2)
void gemm_kernel(const void* __restrict__ A0v, const void* __restrict__ A1v,
                 const unsigned short* __restrict__ W0, const unsigned short* __restrict__ W1,
                 const float* __restrict__ b0, const float* __restrict__ b1,
                 void* O0v, void* O1v,
                 const float* __restrict__ hA, const float* __restrict__ hB,
                 const float* __restrict__ skip)
{
    int z = blockIdx.z;
    const unsigned short* W = z ? W1 : W0;
    const float* bias = z ? b1 : b0;
    int mBase = blockIdx.x * 128;
    int nBase = blockIdx.y * 128;

    __shared__ __align__(16) unsigned short As[128 * 64];
    __shared__ __align__(16) unsigned short Bs[128 * 64];

    int tid = threadIdx.x;
    int lane = tid & 63, wid = tid >> 6;
    int warpM = wid >> 1, warpN = wid & 1;

    f32x4 acc[4][4];
    #pragma unroll
    for (int i = 0; i < 4; ++i)
        #pragma unroll
        for (int j = 0; j < 4; ++j) acc[i][j] = (f32x4){0.f, 0.f, 0.f, 0.f};

    for (int kt = 0; kt < 4; ++kt) {
        int k0 = kt * 64;
        __syncthreads();
        #pragma unroll
        for (int i = 0; i < 4; ++i) {
            int c = tid + i * 256;           // 0..1023 16B-chunks
            int row = c >> 3, cc = c & 7;
            int gr = mBase + row; if (gr > NN - 1) gr = NN - 1;
            u32x4 av;
            if constexpr (MODE == 0) {
                const float* A = z ? (const float*)A1v : (const float*)A0v;
                const float* ap = A + (size_t)gr * CC + k0 + cc * 8;
                f32x4 lo = *(const f32x4*)ap;
                f32x4 hi = *(const f32x4*)(ap + 4);
                av[0] = (unsigned)f2bf(lo[0]) | ((unsigned)f2bf(lo[1]) << 16);
                av[1] = (unsigned)f2bf(lo[2]) | ((unsigned)f2bf(lo[3]) << 16);
                av[2] = (unsigned)f2bf(hi[0]) | ((unsigned)f2bf(hi[1]) << 16);
                av[3] = (unsigned)f2bf(hi[2]) | ((unsigned)f2bf(hi[3]) << 16);
            } else {
                const unsigned short* A = z ? (const unsigned short*)A1v : (const unsigned short*)A0v;
                av = *(const u32x4*)(A + (size_t)gr * CC + k0 + cc * 8);
            }
            int sb = row * 128 + ((cc * 16) ^ ((row & 7) << 4));
            *(u32x4*)((char*)As + sb) = av;
            u32x4 bv = *(const u32x4*)(W + (nBase + row) * 256 + k0 + cc * 8);
            *(u32x4*)((char*)Bs + sb) = bv;
        }
        __syncthreads();
        #pragma unroll
        for (int kk = 0; kk < 2; ++kk) {
            bf16x8 af[4], bfr[4];
            int kb = kk * 64 + (lane >> 4) * 16;
            #pragma unroll
            for (int mi = 0; mi < 4; ++mi) {
                int row = warpM * 64 + mi * 16 + (lane & 15);
                int sb = row * 128 + (kb ^ ((row & 7) << 4));
                af[mi] = *(const bf16x8*)((const char*)As + sb);
            }
            #pragma unroll
            for (int ni = 0; ni < 4; ++ni) {
                int row = warpN * 64 + ni * 16 + (lane & 15);
                int sb = row * 128 + (kb ^ ((row & 7) << 4));
                bfr[ni] = *(const bf16x8*)((const char*)Bs + sb);
            }
            #pragma unroll
            for (int mi = 0; mi < 4; ++mi)
                #pragma unroll
                for (int ni = 0; ni < 4; ++ni)
                    acc[mi][ni] = __builtin_amdgcn_mfma_f32_16x16x32_bf16(af[mi], bfr[ni], acc[mi][ni], 0, 0, 0);
        }
    }

    float alpha = 0.f;
    const float* hres = nullptr;
    if constexpr (MODE == 1) {
        alpha = 1.f / (1.f + __expf(-skip[z]));
        hres = z ? hB : hA;
    }

    #pragma unroll
    for (int mi = 0; mi < 4; ++mi) {
        #pragma unroll
        for (int ni = 0; ni < 4; ++ni) {
            int col = nBase + warpN * 64 + ni * 16 + (lane & 15);
            int row0 = mBase + warpM * 64 + mi * 16 + (lane >> 4) * 4;
            float b = bias[col];
            #pragma unroll
            for (int j = 0; j < 4; ++j) {
                int row = row0 + j;
                if (row < NN) {
                    float val = acc[mi][ni][j] + b;
                    if constexpr (MODE == 0) {
                        unsigned short* O = z ? (unsigned short*)O1v : (unsigned short*)O0v;
                        O[(size_t)row * CC + col] = f2bf(val);
                    } else {
                        float* O = (float*)O0v + (size_t)z * NS;
                        float hv = hres[(size_t)row * CC + col];
                        O[(size_t)row * CC + col] = val * alpha + hv * (1.f - alpha);
                    }
                }
            }
        }
    }
}

// ---------------------------------------------------------------------------
// Edge aggregation: one 64-lane wave per dst node; online softmax over its
// incoming edges. Lane l owns cols [4l,4l+4); head = l/8; 8-lane shfl reduce.
// mode 0: write t (bf16). mode 1: out = (prev + t) * 0.5 (bf16 RMW).
// ---------------------------------------------------------------------------
__global__ __launch_bounds__(256)
void agg_kernel(const unsigned short* __restrict__ Q,
                const unsigned short* __restrict__ K,
                const unsigned short* __restrict__ V,
                const int* __restrict__ off,
                const int* __restrict__ srcS,
                const float* __restrict__ pri,
                unsigned short* __restrict__ Tb,
                int mode)
{
    int wid = (blockIdx.x * 256 + threadIdx.x) >> 6;
    if (wid >= NN) return;
    int lane = threadIdx.x & 63;
    int h = lane >> 3;
    float ps = pri[h] * 0.17677669529663687f;  // 1/sqrt(32)

    u32x2 qv = *(const u32x2*)(Q + (size_t)wid * CC + lane * 4);
    float q0 = bf2f(qv[0] & 0xffffu), q1 = bf2f(qv[0] >> 16);
    float q2 = bf2f(qv[1] & 0xffffu), q3 = bf2f(qv[1] >> 16);

    int beg = off[wid], end = off[wid + 1];
    float m = -INFINITY, l = 0.f;
    float a0 = 0.f, a1 = 0.f, a2 = 0.f, a3 = 0.f;

    for (int e = beg; e < end; ++e) {
        int s = srcS[e];
        u32x2 kv = *(const u32x2*)(K + (size_t)s * CC + lane * 4);
        u32x2 vv = *(const u32x2*)(V + (size_t)s * CC + lane * 4);
        float d = q0 * bf2f(kv[0] & 0xffffu) + q1 * bf2f(kv[0] >> 16)
                + q2 * bf2f(kv[1] & 0xffffu) + q3 * bf2f(kv[1] >> 16);
        d += __shfl_xor(d, 1);
        d += __shfl_xor(d, 2);
        d += __shfl_xor(d, 4);
        float sc = d * ps;
        float mn = fmaxf(m, sc);
        float cs = __expf(m - mn);
        float p  = __expf(sc - mn);
        l = l * cs + p;
        a0 = a0 * cs + p * bf2f(vv[0] & 0xffffu);
        a1 = a1 * cs + p * bf2f(vv[0] >> 16);
        a2 = a2 * cs + p * bf2f(vv[1] & 0xffffu);
        a3 = a3 * cs + p * bf2f(vv[1] >> 16);
        m = mn;
    }
    float inv = (l > 0.f) ? 1.f / l : 0.f;
    float r0 = a0 * inv, r1 = a1 * inv, r2 = a2 * inv, r3 = a3 * inv;
    unsigned short* out = Tb + (size_t)wid * CC + lane * 4;
    if (mode) {
        u32x2 prev = *(const u32x2*)out;
        r0 = (r0 + bf2f(prev[0] & 0xffffu)) * 0.5f;
        r1 = (r1 + bf2f(prev[0] >> 16)) * 0.5f;
        r2 = (r2 + bf2f(prev[1] & 0xffffu)) * 0.5f;
        r3 = (r3 + bf2f(prev[1] >> 16)) * 0.5f;
    }
    u32x2 o;
    o[0] = (unsigned)f2bf(r0) | ((unsigned)f2bf(r1) << 16);
    o[1] = (unsigned)f2bf(r2) | ((unsigned)f2bf(r3) << 16);
    *(u32x2*)out = o;
}

// ---------------------------------------------------------------------------
extern "C" void kernel_launch(void* const* d_in, const int* in_sizes, int n_in,
                              void* d_out, int out_size, void* d_ws, size_t ws_size,
                              hipStream_t stream)
{
    const float* hA = (const float*)d_in[0];
    const float* hB = (const float*)d_in[1];
    const int* src0 = (const int*)d_in[2];
    const int* dst0 = (const int*)d_in[3];
    const int* src1 = (const int*)d_in[4];
    const int* dst1 = (const int*)d_in[5];
    const int* src2 = (const int*)d_in[6];
    const int* dst2 = (const int*)d_in[7];
    const float* Wk = (const float*)d_in[8];
    const float* bk = (const float*)d_in[9];
    const float* Wq = (const float*)d_in[10];
    const float* bq = (const float*)d_in[11];
    const float* Wv = (const float*)d_in[12];
    const float* bv = (const float*)d_in[13];
    const float* Wa = (const float*)d_in[14];
    const float* ba = (const float*)d_in[15];
    const float* rel_att = (const float*)d_in[16];
    const float* rel_msg = (const float*)d_in[17];
    const float* rel_pri = (const float*)d_in[18];
    const float* skip = (const float*)d_in[19];

    char* w = (char*)d_ws;
    auto alloc = [&](size_t bytes) {
        char* p = w;
        w += (bytes + 255) & ~(size_t)255;
        return p;
    };
    // total ~166 MB
    unsigned short* WT  = (unsigned short*)alloc((size_t)10 * 65536 * 2);
    float* ball         = (float*)alloc((size_t)8 * 256 * 4);
    unsigned short* Qb  = (unsigned short*)alloc((size_t)2 * NS * 2);  // q per type
    unsigned short* Kb  = (unsigned short*)alloc((size_t)NS * 2);      // per-relation, reused
    unsigned short* Vb  = (unsigned short*)alloc((size_t)NS * 2);
    unsigned short* Tb  = (unsigned short*)alloc((size_t)2 * NS * 2);  // t per type
    int* counts         = (int*)alloc((size_t)3 * NN * 4);
    int* offs           = (int*)alloc((size_t)3 * (NN + 1) * 4);
    int* cur            = (int*)alloc((size_t)3 * NN * 4);
    int* srcS           = (int*)alloc((size_t)3 * EE * 4);

    zero_kernel<<<586, 256, 0, stream>>>(counts, 3 * NN);
    prep_kernel<<<2568, 256, 0, stream>>>(Wk, bk, Wq, bq, Wv, bv, Wa, rel_att, rel_msg, WT, ball);
    hist_kernel<<<9375, 256, 0, stream>>>(dst0, dst1, dst2, counts);
    scan_kernel<<<3, 1024, 0, stream>>>(counts, offs, cur);
    scatter_kernel<<<9375, 256, 0, stream>>>(src0, dst0, src1, dst1, src2, dst2, cur, srcS);

    dim3 g(391, 2, 2);
    // Q for both types: slots 0,1
    gemm_kernel<0><<<g, 256, 0, stream>>>(hA, hB, WT, WT + 65536, ball, ball + 256,
                                          Qb, Qb + NS, nullptr, nullptr, nullptr);

    for (int r = 0; r < 3; ++r) {
        const float* hs = (r == 1) ? hB : hA;   // source type: 0,1,0
        // K (slot 2+r) and V (slot 5+r) for this relation
        gemm_kernel<0><<<g, 256, 0, stream>>>(hs, hs,
                                              WT + (2 + r) * 65536, WT + (5 + r) * 65536,
                                              ball + (2 + r) * 256, ball + (5 + r) * 256,
                                              Kb, Vb, nullptr, nullptr, nullptr);
        const unsigned short* Q = (r == 1) ? Qb : Qb + NS;  // dst type: 1,0,1
        unsigned short* Tout    = (r == 1) ? Tb : Tb + NS;
        int mode = (r == 2) ? 1 : 0;  // r2 accumulates with r0 and halves
        agg_kernel<<<12500, 256, 0, stream>>>(Q, Kb, Vb, offs + r * (NN + 1), srcS + r * EE,
                                              rel_pri + r * 8, Tout, mode);
    }

    // Output GEMM: (T @ Wa + ba)*alpha + h*(1-alpha)
    gemm_kernel<1><<<g, 256, 0, stream>>>(Tb, Tb + NS, WT + 8 * 65536, WT + 9 * 65536,
                                          ba, ba + 256, d_out, nullptr, hA, hB, skip);
}

// Round 3
// 1007.379 us; speedup vs baseline: 1.0348x; 1.0348x over previous
//
#include <hip/hip_runtime.h>
#include <math.h>

#define NN 50000
#define EE 800000
#define CC 256
#define NS (NN * CC)
#define XBLK 9375          // extra-work blocks (hist/scatter): 9375*256 = 3*EE
#define TILES_PER_SLOT 782 // 391 M-tiles * 2 N-tiles

typedef __attribute__((ext_vector_type(4))) float f32x4;
typedef __attribute__((ext_vector_type(8))) short bf16x8;
typedef __attribute__((ext_vector_type(4))) unsigned int u32x4;
typedef __attribute__((ext_vector_type(2))) unsigned int u32x2;

__device__ __forceinline__ float bf2f(unsigned int u) {
    union { unsigned int i; float f; } c; c.i = u << 16; return c.f;
}
__device__ __forceinline__ unsigned short f2bf(float f) {
    union { float f; unsigned int i; } c; c.f = f;
    unsigned int u = c.i;
    u += 0x7fffu + ((u >> 16) & 1u);
    return (unsigned short)(u >> 16);
}

struct Slots4 {
    const float* A[4];
    const unsigned short* W[4];
    const float* bias[4];
    unsigned short* O[4];
};

// ---------------------------------------------------------------------------
// setup: zero counts + prep weights (fused).
// WT slots: 0-1 WqT(t), 2-4 WckT(r), 5-7 WcvT(r), 8-9 WaT(t)
// ball slots: 0-1 bq(t), 2-4 folded bk(r), 5-7 folded bv(r)
// ---------------------------------------------------------------------------
__global__ void setup_kernel(const float* __restrict__ Wk, const float* __restrict__ bk,
                             const float* __restrict__ Wq, const float* __restrict__ bq,
                             const float* __restrict__ Wv, const float* __restrict__ bv,
                             const float* __restrict__ Wa,
                             const float* __restrict__ rel_att, const float* __restrict__ rel_msg,
                             unsigned short* __restrict__ WT, float* __restrict__ ball,
                             int* __restrict__ counts)
{
    int b = blockIdx.x;
    if (b < 586) {
        int i = b * 256 + threadIdx.x;
        if (i < 3 * NN) counts[i] = 0;
        return;
    }
    int id = (b - 586) * 256 + threadIdx.x;
    const int ts[3] = {0, 1, 0};  // source node type per relation
    if (id < 2 * 65536) {
        int t = id >> 16, rem = id & 65535;
        int n = rem >> 8, k = rem & 255;
        WT[t * 65536 + n * 256 + k] = f2bf(Wq[t * 65536 + k * 256 + n]);
    } else if (id < 5 * 65536) {
        int id2 = id - 2 * 65536;
        int r = id2 >> 16, rem = id2 & 65535;
        int n = rem >> 8, k = rem & 255;
        int h = n >> 5, j = n & 31;
        const float* wkb = Wk + ts[r] * 65536 + k * 256 + h * 32;
        const float* ab  = rel_att + r * 8192 + h * 1024 + j;
        float s = 0.f;
        #pragma unroll 8
        for (int d = 0; d < 32; ++d) s += wkb[d] * ab[d * 32];
        WT[(2 + r) * 65536 + n * 256 + k] = f2bf(s);
    } else if (id < 8 * 65536) {
        int id2 = id - 5 * 65536;
        int r = id2 >> 16, rem = id2 & 65535;
        int n = rem >> 8, k = rem & 255;
        int h = n >> 5, j = n & 31;
        const float* wvb = Wv + ts[r] * 65536 + k * 256 + h * 32;
        const float* mb  = rel_msg + r * 8192 + h * 1024 + j;
        float s = 0.f;
        #pragma unroll 8
        for (int d = 0; d < 32; ++d) s += wvb[d] * mb[d * 32];
        WT[(5 + r) * 65536 + n * 256 + k] = f2bf(s);
    } else if (id < 10 * 65536) {
        int id2 = id - 8 * 65536;
        int t = id2 >> 16, rem = id2 & 65535;
        int n = rem >> 8, k = rem & 255;
        WT[(8 + t) * 65536 + n * 256 + k] = f2bf(Wa[t * 65536 + k * 256 + n]);
    } else if (id < 10 * 65536 + 2048) {
        int id2 = id - 10 * 65536;
        int z = id2 >> 8, c = id2 & 255;
        float v;
        if (z < 2) {
            v = bq[z * 256 + c];
        } else if (z < 5) {
            int r = z - 2, h = c >> 5, j = c & 31;
            const float* bkb = bk + ts[r] * 256 + h * 32;
            const float* ab  = rel_att + r * 8192 + h * 1024 + j;
            v = 0.f;
            for (int d = 0; d < 32; ++d) v += bkb[d] * ab[d * 32];
        } else {
            int r = z - 5, h = c >> 5, j = c & 31;
            const float* bvb = bv + ts[r] * 256 + h * 32;
            const float* mb  = rel_msg + r * 8192 + h * 1024 + j;
            v = 0.f;
            for (int d = 0; d < 32; ++d) v += bvb[d] * mb[d * 32];
        }
        ball[z * 256 + c] = v;
    }
}

__global__ __launch_bounds__(1024) void scan_kernel(const int* __restrict__ counts,
                                                    int* __restrict__ offsets,
                                                    int* __restrict__ cur)
{
    int r = blockIdx.x;
    const int* c = counts + r * NN;
    int* off = offsets + r * (NN + 1);
    int* cu  = cur + r * NN;
    int t = threadIdx.x, lane = t & 63, wid = t >> 6;
    __shared__ int wsum[16];
    __shared__ int stot;
    int carry = 0;
    for (int base = 0; base < NN; base += 1024) {
        int i = base + t;
        int x = (i < NN) ? c[i] : 0;
        int v = x;
        #pragma unroll
        for (int ofs = 1; ofs < 64; ofs <<= 1) {
            int y = __shfl_up(v, ofs);
            if (lane >= ofs) v += y;
        }
        if (lane == 63) wsum[wid] = v;
        __syncthreads();
        if (t < 16) {
            int wv = wsum[t];
            #pragma unroll
            for (int ofs = 1; ofs < 16; ofs <<= 1) {
                int y = __shfl_up(wv, ofs);
                if (t >= ofs) wv += y;
            }
            wsum[t] = wv;
            if (t == 15) stot = wv;
        }
        __syncthreads();
        int woff = (wid > 0) ? wsum[wid - 1] : 0;
        int excl = carry + woff + v - x;
        if (i < NN) { off[i] = excl; cu[i] = excl; }
        carry += stot;
        __syncthreads();
    }
    if (t == 0) off[NN] = carry;
}

// ---------------------------------------------------------------------------
// GEMM block: [128 rows of A(f32, convert to bf16)] x [128 cols of W(bf16,
// pre-transposed [n][k])], BK=64, 4 waves, XOR-swizzled LDS, bf16 out + bias.
// ---------------------------------------------------------------------------
__device__ __forceinline__ void gemm_block_f32(const float* __restrict__ A,
                                               const unsigned short* __restrict__ W,
                                               const float* __restrict__ bias,
                                               unsigned short* __restrict__ O,
                                               int tt)
{
    __shared__ __align__(16) unsigned short As[128 * 64];
    __shared__ __align__(16) unsigned short Bs[128 * 64];

    int mBase = (tt >> 1) * 128;
    int nBase = (tt & 1) * 128;
    int tid = threadIdx.x;
    int lane = tid & 63, wid = tid >> 6;
    int warpM = wid >> 1, warpN = wid & 1;

    f32x4 acc[4][4];
    #pragma unroll
    for (int i = 0; i < 4; ++i)
        #pragma unroll
        for (int j = 0; j < 4; ++j) acc[i][j] = (f32x4){0.f, 0.f, 0.f, 0.f};

    for (int kt = 0; kt < 4; ++kt) {
        int k0 = kt * 64;
        __syncthreads();
        #pragma unroll
        for (int i = 0; i < 4; ++i) {
            int c = tid + i * 256;           // 0..1023 16B-chunks
            int row = c >> 3, cc = c & 7;
            int gr = mBase + row; if (gr > NN - 1) gr = NN - 1;
            const float* ap = A + (size_t)gr * CC + k0 + cc * 8;
            f32x4 lo = *(const f32x4*)ap;
            f32x4 hi = *(const f32x4*)(ap + 4);
            u32x4 av;
            av[0] = (unsigned)f2bf(lo[0]) | ((unsigned)f2bf(lo[1]) << 16);
            av[1] = (unsigned)f2bf(lo[2]) | ((unsigned)f2bf(lo[3]) << 16);
            av[2] = (unsigned)f2bf(hi[0]) | ((unsigned)f2bf(hi[1]) << 16);
            av[3] = (unsigned)f2bf(hi[2]) | ((unsigned)f2bf(hi[3]) << 16);
            int sb = row * 128 + ((cc * 16) ^ ((row & 7) << 4));
            *(u32x4*)((char*)As + sb) = av;
            u32x4 bv = *(const u32x4*)(W + (nBase + row) * 256 + k0 + cc * 8);
            *(u32x4*)((char*)Bs + sb) = bv;
        }
        __syncthreads();
        #pragma unroll
        for (int kk = 0; kk < 2; ++kk) {
            bf16x8 af[4], bfr[4];
            int kb = kk * 64 + (lane >> 4) * 16;
            #pragma unroll
            for (int mi = 0; mi < 4; ++mi) {
                int row = warpM * 64 + mi * 16 + (lane & 15);
                int sb = row * 128 + (kb ^ ((row & 7) << 4));
                af[mi] = *(const bf16x8*)((const char*)As + sb);
            }
            #pragma unroll
            for (int ni = 0; ni < 4; ++ni) {
                int row = warpN * 64 + ni * 16 + (lane & 15);
                int sb = row * 128 + (kb ^ ((row & 7) << 4));
                bfr[ni] = *(const bf16x8*)((const char*)Bs + sb);
            }
            #pragma unroll
            for (int mi = 0; mi < 4; ++mi)
                #pragma unroll
                for (int ni = 0; ni < 4; ++ni)
                    acc[mi][ni] = __builtin_amdgcn_mfma_f32_16x16x32_bf16(af[mi], bfr[ni], acc[mi][ni], 0, 0, 0);
        }
    }

    #pragma unroll
    for (int mi = 0; mi < 4; ++mi) {
        #pragma unroll
        for (int ni = 0; ni < 4; ++ni) {
            int col = nBase + warpN * 64 + ni * 16 + (lane & 15);
            int row0 = mBase + warpM * 64 + mi * 16 + (lane >> 4) * 4;
            float b = bias[col];
            #pragma unroll
            for (int j = 0; j < 4; ++j) {
                int row = row0 + j;
                if (row < NN) O[(size_t)row * CC + col] = f2bf(acc[mi][ni][j] + b);
            }
        }
    }
}

// ---------------------------------------------------------------------------
// Fused: blocks [0,XBLK) do hist (KIND=0) or scatter (KIND=1);
// blocks [XBLK, XBLK+4*782) do GEMM for 4 slots.
// ---------------------------------------------------------------------------
template<int KIND>
__global__ __launch_bounds__(256, 2)
void fused_kernel(Slots4 sl,
                  const int* __restrict__ s0, const int* __restrict__ s1, const int* __restrict__ s2,
                  const int* __restrict__ d0, const int* __restrict__ d1, const int* __restrict__ d2,
                  int* __restrict__ cc_, int* __restrict__ srcS)
{
    int b = blockIdx.x;
    if (b < XBLK) {
        int i = b * 256 + threadIdx.x;
        if constexpr (KIND == 0) {
            if (i < EE)            atomicAdd(&cc_[d0[i]], 1);
            else if (i < 2 * EE)   atomicAdd(&cc_[NN + d1[i - EE]], 1);
            else                   atomicAdd(&cc_[2 * NN + d2[i - 2 * EE]], 1);
        } else {
            int r, e;
            const int *sp, *dp;
            if (i < EE)          { r = 0; e = i;          sp = s0; dp = d0; }
            else if (i < 2 * EE) { r = 1; e = i - EE;     sp = s1; dp = d1; }
            else                 { r = 2; e = i - 2 * EE; sp = s2; dp = d2; }
            int dst = dp[e];
            int pos = atomicAdd(&cc_[r * NN + dst], 1);
            srcS[r * EE + pos] = sp[e];
        }
        return;
    }
    int t = b - XBLK;
    int slot = t / TILES_PER_SLOT;
    int tt = t - slot * TILES_PER_SLOT;
    gemm_block_f32(sl.A[slot], sl.W[slot], sl.bias[slot], sl.O[slot], tt);
}

// ---------------------------------------------------------------------------
// Output GEMM (MODE1 of old template): A bf16, out f32 with skip-residual.
// ---------------------------------------------------------------------------
__global__ __launch_bounds__(256, 2)
void out_gemm_kernel(const unsigned short* __restrict__ A0, const unsigned short* __restrict__ A1,
                     const unsigned short* __restrict__ W0, const unsigned short* __restrict__ W1,
                     const float* __restrict__ b0, const float* __restrict__ b1,
                     float* __restrict__ OutF,
                     const float* __restrict__ hA, const float* __restrict__ hB,
                     const float* __restrict__ skip)
{
    int z = blockIdx.z;
    const unsigned short* A = z ? A1 : A0;
    const unsigned short* W = z ? W1 : W0;
    const float* bias = z ? b1 : b0;
    int mBase = blockIdx.x * 128;
    int nBase = blockIdx.y * 128;

    __shared__ __align__(16) unsigned short As[128 * 64];
    __shared__ __align__(16) unsigned short Bs[128 * 64];

    int tid = threadIdx.x;
    int lane = tid & 63, wid = tid >> 6;
    int warpM = wid >> 1, warpN = wid & 1;

    f32x4 acc[4][4];
    #pragma unroll
    for (int i = 0; i < 4; ++i)
        #pragma unroll
        for (int j = 0; j < 4; ++j) acc[i][j] = (f32x4){0.f, 0.f, 0.f, 0.f};

    for (int kt = 0; kt < 4; ++kt) {
        int k0 = kt * 64;
        __syncthreads();
        #pragma unroll
        for (int i = 0; i < 4; ++i) {
            int c = tid + i * 256;
            int row = c >> 3, cc = c & 7;
            int gr = mBase + row; if (gr > NN - 1) gr = NN - 1;
            u32x4 av = *(const u32x4*)(A + (size_t)gr * CC + k0 + cc * 8);
            int sb = row * 128 + ((cc * 16) ^ ((row & 7) << 4));
            *(u32x4*)((char*)As + sb) = av;
            u32x4 bv = *(const u32x4*)(W + (nBase + row) * 256 + k0 + cc * 8);
            *(u32x4*)((char*)Bs + sb) = bv;
        }
        __syncthreads();
        #pragma unroll
        for (int kk = 0; kk < 2; ++kk) {
            bf16x8 af[4], bfr[4];
            int kb = kk * 64 + (lane >> 4) * 16;
            #pragma unroll
            for (int mi = 0; mi < 4; ++mi) {
                int row = warpM * 64 + mi * 16 + (lane & 15);
                int sb = row * 128 + (kb ^ ((row & 7) << 4));
                af[mi] = *(const bf16x8*)((const char*)As + sb);
            }
            #pragma unroll
            for (int ni = 0; ni < 4; ++ni) {
                int row = warpN * 64 + ni * 16 + (lane & 15);
                int sb = row * 128 + (kb ^ ((row & 7) << 4));
                bfr[ni] = *(const bf16x8*)((const char*)Bs + sb);
            }
            #pragma unroll
            for (int mi = 0; mi < 4; ++mi)
                #pragma unroll
                for (int ni = 0; ni < 4; ++ni)
                    acc[mi][ni] = __builtin_amdgcn_mfma_f32_16x16x32_bf16(af[mi], bfr[ni], acc[mi][ni], 0, 0, 0);
        }
    }

    float alpha = 1.f / (1.f + __expf(-skip[z]));
    const float* hres = z ? hB : hA;

    #pragma unroll
    for (int mi = 0; mi < 4; ++mi) {
        #pragma unroll
        for (int ni = 0; ni < 4; ++ni) {
            int col = nBase + warpN * 64 + ni * 16 + (lane & 15);
            int row0 = mBase + warpM * 64 + mi * 16 + (lane >> 4) * 4;
            float b = bias[col];
            #pragma unroll
            for (int j = 0; j < 4; ++j) {
                int row = row0 + j;
                if (row < NN) {
                    float val = acc[mi][ni][j] + b;
                    float hv = hres[(size_t)row * CC + col];
                    ((float*)OutF)[(size_t)z * NS + (size_t)row * CC + col] = val * alpha + hv * (1.f - alpha);
                }
            }
        }
    }
}

// ---------------------------------------------------------------------------
// Edge aggregation, all relations in one launch. One wave per (dst, relgroup).
// Lane l owns cols [4l,4l+4); head = l/8; 8-lane shfl reduce; online softmax.
// Wave w < NN: type-B dst (r0 then r2, result averaged). w in [NN,2NN): type-A
// dst (r1). srcS indices prefetched 64-wide and broadcast via shfl.
// ---------------------------------------------------------------------------
__device__ __forceinline__ void agg_pass(const unsigned short* __restrict__ K,
                                         const unsigned short* __restrict__ V,
                                         const int* __restrict__ srcS,
                                         int beg, int end, int lane,
                                         float q0, float q1, float q2, float q3, float ps,
                                         float& o0, float& o1, float& o2, float& o3)
{
    float m = -INFINITY, l = 0.f;
    float a0 = 0.f, a1 = 0.f, a2 = 0.f, a3 = 0.f;
    int n = end - beg;
    int idx = 0;
    if (n > 0) {
        int p = beg + lane;
        idx = srcS[p < end ? p : end - 1];
    }
    for (int j = 0; j < n; ++j) {
        if (j && (j & 63) == 0) {
            int p = beg + j + lane;
            idx = srcS[p < end ? p : end - 1];
        }
        int s = __shfl(idx, j & 63);
        u32x2 kv = *(const u32x2*)(K + (size_t)s * CC + lane * 4);
        u32x2 vv = *(const u32x2*)(V + (size_t)s * CC + lane * 4);
        float d = q0 * bf2f(kv[0] & 0xffffu) + q1 * bf2f(kv[0] >> 16)
                + q2 * bf2f(kv[1] & 0xffffu) + q3 * bf2f(kv[1] >> 16);
        d += __shfl_xor(d, 1);
        d += __shfl_xor(d, 2);
        d += __shfl_xor(d, 4);
        float sc = d * ps;
        float mn = fmaxf(m, sc);
        float cs = __expf(m - mn);
        float p  = __expf(sc - mn);
        l = l * cs + p;
        a0 = a0 * cs + p * bf2f(vv[0] & 0xffffu);
        a1 = a1 * cs + p * bf2f(vv[0] >> 16);
        a2 = a2 * cs + p * bf2f(vv[1] & 0xffffu);
        a3 = a3 * cs + p * bf2f(vv[1] >> 16);
        m = mn;
    }
    float inv = (l > 0.f) ? 1.f / l : 0.f;
    o0 = a0 * inv; o1 = a1 * inv; o2 = a2 * inv; o3 = a3 * inv;
}

__global__ __launch_bounds__(256)
void agg_all_kernel(const unsigned short* __restrict__ Q0, const unsigned short* __restrict__ Q1,
                    const unsigned short* __restrict__ K0, const unsigned short* __restrict__ V0,
                    const unsigned short* __restrict__ K1, const unsigned short* __restrict__ V1,
                    const unsigned short* __restrict__ K2, const unsigned short* __restrict__ V2,
                    const int* __restrict__ offs, const int* __restrict__ srcS,
                    const float* __restrict__ rel_pri,
                    unsigned short* __restrict__ TbA, unsigned short* __restrict__ TbB)
{
    int w = (blockIdx.x * 256 + threadIdx.x) >> 6;
    int lane = threadIdx.x & 63;
    int h = lane >> 3;
    const float rs = 0.17677669529663687f;  // 1/sqrt(32)

    if (w < NN) {
        int d = w;
        u32x2 qv = *(const u32x2*)(Q1 + (size_t)d * CC + lane * 4);
        float q0 = bf2f(qv[0] & 0xffffu), q1 = bf2f(qv[0] >> 16);
        float q2 = bf2f(qv[1] & 0xffffu), q3 = bf2f(qv[1] >> 16);
        float x0, x1, x2, x3, y0, y1, y2, y3;
        agg_pass(K0, V0, srcS, offs[d], offs[d + 1], lane,
                 q0, q1, q2, q3, rel_pri[h] * rs, x0, x1, x2, x3);
        const int* off2 = offs + 2 * (NN + 1);
        agg_pass(K2, V2, srcS + 2 * EE, off2[d], off2[d + 1], lane,
                 q0, q1, q2, q3, rel_pri[16 + h] * rs, y0, y1, y2, y3);
        unsigned short* out = TbB + (size_t)d * CC + lane * 4;
        u32x2 o;
        o[0] = (unsigned)f2bf((x0 + y0) * 0.5f) | ((unsigned)f2bf((x1 + y1) * 0.5f) << 16);
        o[1] = (unsigned)f2bf((x2 + y2) * 0.5f) | ((unsigned)f2bf((x3 + y3) * 0.5f) << 16);
        *(u32x2*)out = o;
    } else if (w < 2 * NN) {
        int d = w - NN;
        u32x2 qv = *(const u32x2*)(Q0 + (size_t)d * CC + lane * 4);
        float q0 = bf2f(qv[0] & 0xffffu), q1 = bf2f(qv[0] >> 16);
        float q2 = bf2f(qv[1] & 0xffffu), q3 = bf2f(qv[1] >> 16);
        float x0, x1, x2, x3;
        const int* off1 = offs + (NN + 1);
        agg_pass(K1, V1, srcS + EE, off1[d], off1[d + 1], lane,
                 q0, q1, q2, q3, rel_pri[8 + h] * rs, x0, x1, x2, x3);
        unsigned short* out = TbA + (size_t)d * CC + lane * 4;
        u32x2 o;
        o[0] = (unsigned)f2bf(x0) | ((unsigned)f2bf(x1) << 16);
        o[1] = (unsigned)f2bf(x2) | ((unsigned)f2bf(x3) << 16);
        *(u32x2*)out = o;
    }
}

// ---------------------------------------------------------------------------
extern "C" void kernel_launch(void* const* d_in, const int* in_sizes, int n_in,
                              void* d_out, int out_size, void* d_ws, size_t ws_size,
                              hipStream_t stream)
{
    const float* hA = (const float*)d_in[0];
    const float* hB = (const float*)d_in[1];
    const int* src0 = (const int*)d_in[2];
    const int* dst0 = (const int*)d_in[3];
    const int* src1 = (const int*)d_in[4];
    const int* dst1 = (const int*)d_in[5];
    const int* src2 = (const int*)d_in[6];
    const int* dst2 = (const int*)d_in[7];
    const float* Wk = (const float*)d_in[8];
    const float* bk = (const float*)d_in[9];
    const float* Wq = (const float*)d_in[10];
    const float* bq = (const float*)d_in[11];
    const float* Wv = (const float*)d_in[12];
    const float* bv = (const float*)d_in[13];
    const float* Wa = (const float*)d_in[14];
    const float* ba = (const float*)d_in[15];
    const float* rel_att = (const float*)d_in[16];
    const float* rel_msg = (const float*)d_in[17];
    const float* rel_pri = (const float*)d_in[18];
    const float* skip = (const float*)d_in[19];

    char* w = (char*)d_ws;
    auto alloc = [&](size_t bytes) {
        char* p = w;
        w += (bytes + 255) & ~(size_t)255;
        return p;
    };
    // ws total ~166.3 MB (known-good budget)
    unsigned short* WT  = (unsigned short*)alloc((size_t)10 * 65536 * 2);
    float* ball         = (float*)alloc((size_t)8 * 256 * 4);
    unsigned short* Qb  = (unsigned short*)alloc((size_t)2 * NS * 2);  // Q0,Q1
    unsigned short* Kb0 = (unsigned short*)alloc((size_t)NS * 2);      // K r0
    unsigned short* Kb1 = (unsigned short*)alloc((size_t)NS * 2);      // K r1
    unsigned short* Tb  = (unsigned short*)alloc((size_t)2 * NS * 2);  // t per type
    int* counts         = (int*)alloc((size_t)3 * NN * 4);
    int* offs           = (int*)alloc((size_t)3 * (NN + 1) * 4);
    int* cur            = (int*)alloc((size_t)3 * NN * 4);
    int* srcS           = (int*)alloc((size_t)3 * EE * 4);

    // 4 bf16 QKV slots live in d_out (102.4 MB, dead until final GEMM)
    unsigned short* dob = (unsigned short*)d_out;
    unsigned short* K2d = dob + 0 * (size_t)NS;
    unsigned short* V0d = dob + 1 * (size_t)NS;
    unsigned short* V1d = dob + 2 * (size_t)NS;
    unsigned short* V2d = dob + 3 * (size_t)NS;

    setup_kernel<<<3154, 256, 0, stream>>>(Wk, bk, Wq, bq, Wv, bv, Wa,
                                           rel_att, rel_msg, WT, ball, counts);

    // fused1: hist + GEMM slots {Q0, Q1, K0, K1}
    Slots4 s1;
    s1.A[0] = hA;  s1.W[0] = WT + 0 * 65536; s1.bias[0] = ball + 0 * 256; s1.O[0] = Qb;
    s1.A[1] = hB;  s1.W[1] = WT + 1 * 65536; s1.bias[1] = ball + 1 * 256; s1.O[1] = Qb + NS;
    s1.A[2] = hA;  s1.W[2] = WT + 2 * 65536; s1.bias[2] = ball + 2 * 256; s1.O[2] = Kb0;
    s1.A[3] = hB;  s1.W[3] = WT + 3 * 65536; s1.bias[3] = ball + 3 * 256; s1.O[3] = Kb1;
    fused_kernel<0><<<XBLK + 4 * TILES_PER_SLOT, 256, 0, stream>>>(
        s1, src0, src1, src2, dst0, dst1, dst2, counts, nullptr);

    scan_kernel<<<3, 1024, 0, stream>>>(counts, offs, cur);

    // fused2: scatter + GEMM slots {K2, V0, V1, V2} (outputs in d_out)
    Slots4 s2;
    s2.A[0] = hA;  s2.W[0] = WT + 4 * 65536; s2.bias[0] = ball + 4 * 256; s2.O[0] = K2d;
    s2.A[1] = hA;  s2.W[1] = WT + 5 * 65536; s2.bias[1] = ball + 5 * 256; s2.O[1] = V0d;
    s2.A[2] = hB;  s2.W[2] = WT + 6 * 65536; s2.bias[2] = ball + 6 * 256; s2.O[2] = V1d;
    s2.A[3] = hA;  s2.W[3] = WT + 7 * 65536; s2.bias[3] = ball + 7 * 256; s2.O[3] = V2d;
    fused_kernel<1><<<XBLK + 4 * TILES_PER_SLOT, 256, 0, stream>>>(
        s2, src0, src1, src2, dst0, dst1, dst2, cur, srcS);

    // all 3 relations' aggregation in one launch
    agg_all_kernel<<<25000, 256, 0, stream>>>(Qb, Qb + NS, Kb0, V0d, Kb1, V1d, K2d, V2d,
                                              offs, srcS, rel_pri, Tb, Tb + NS);

    // output GEMM overwrites d_out (reads only Tb/hA/hB/WT)
    out_gemm_kernel<<<dim3(391, 2, 2), 256, 0, stream>>>(
        Tb, Tb + NS, WT + 8 * 65536, WT + 9 * 65536, ba, ba + 256,
        (float*)d_out, hA, hB, skip);
}

// Round 4
// 711.886 us; speedup vs baseline: 1.4643x; 1.4151x over previous
//
#include <hip/hip_runtime.h>
#include <math.h>

#define NN 50000
#define EE 800000
#define CC 256
#define NS (NN * CC)
#define NBK 782        // dst buckets per relation (64 dsts each; 782*64 >= NN)
#define BCAP 2048      // LDS capacity per bucket in P2 (mean 1023, +32 sigma)
#define P1T 2048       // edges per P0/P1 tile
#define NT1 391        // tiles per relation = ceil(EE / P1T)

typedef __attribute__((ext_vector_type(4))) float f32x4;
typedef __attribute__((ext_vector_type(8))) short bf16x8;
typedef __attribute__((ext_vector_type(4))) unsigned int u32x4;
typedef __attribute__((ext_vector_type(2))) unsigned int u32x2;

__device__ __forceinline__ float bf2f(unsigned int u) {
    union { unsigned int i; float f; } c; c.i = u << 16; return c.f;
}
__device__ __forceinline__ unsigned short f2bf(float f) {
    union { float f; unsigned int i; } c; c.f = f;
    unsigned int u = c.i;
    u += 0x7fffu + ((u >> 16) & 1u);
    return (unsigned short)(u >> 16);
}

// ---------------------------------------------------------------------------
// setup: prep weights (blocks [0,2568)) + P0 bucket histogram (blocks >= 2568).
// WT slots: 0-1 WqT(t), 2-4 WckT(r), 5-7 WcvT(r), 8-9 WaT(t)
// ball slots: 0-1 bq(t), 2-4 folded bk(r), 5-7 folded bv(r)
// bcnt zeroed by hipMemsetAsync before this kernel.
// ---------------------------------------------------------------------------
__global__ void setup_kernel(const float* __restrict__ Wk, const float* __restrict__ bk,
                             const float* __restrict__ Wq, const float* __restrict__ bq,
                             const float* __restrict__ Wv, const float* __restrict__ bv,
                             const float* __restrict__ Wa,
                             const float* __restrict__ rel_att, const float* __restrict__ rel_msg,
                             unsigned short* __restrict__ WT, float* __restrict__ ball,
                             const int* __restrict__ d0, const int* __restrict__ d1,
                             const int* __restrict__ d2, int* __restrict__ bcnt)
{
    int b = blockIdx.x;
    const int ts[3] = {0, 1, 0};  // source node type per relation
    if (b >= 2568) {
        // P0: bucket histogram
        int bb = b - 2568;               // 0 .. 3*NT1-1
        int r = bb / NT1, tile = bb - r * NT1;
        const int* dp = r == 0 ? d0 : (r == 1 ? d1 : d2);
        __shared__ int hist[NBK];
        for (int i = threadIdx.x; i < NBK; i += 256) hist[i] = 0;
        __syncthreads();
        int base = tile * P1T;
        int lim = base + P1T; if (lim > EE) lim = EE;
        for (int i = base + threadIdx.x; i < lim; i += 256)
            atomicAdd(&hist[dp[i] >> 6], 1);
        __syncthreads();
        for (int i = threadIdx.x; i < NBK; i += 256)
            if (hist[i]) atomicAdd(&bcnt[r * NBK + i], hist[i]);
        return;
    }
    int id = b * 256 + threadIdx.x;
    if (id < 2 * 65536) {
        int t = id >> 16, rem = id & 65535;
        int n = rem >> 8, k = rem & 255;
        WT[t * 65536 + n * 256 + k] = f2bf(Wq[t * 65536 + k * 256 + n]);
    } else if (id < 5 * 65536) {
        int id2 = id - 2 * 65536;
        int r = id2 >> 16, rem = id2 & 65535;
        int n = rem >> 8, k = rem & 255;
        int h = n >> 5, j = n & 31;
        const float* wkb = Wk + ts[r] * 65536 + k * 256 + h * 32;
        const float* ab  = rel_att + r * 8192 + h * 1024 + j;
        float s = 0.f;
        #pragma unroll 8
        for (int d = 0; d < 32; ++d) s += wkb[d] * ab[d * 32];
        WT[(2 + r) * 65536 + n * 256 + k] = f2bf(s);
    } else if (id < 8 * 65536) {
        int id2 = id - 5 * 65536;
        int r = id2 >> 16, rem = id2 & 65535;
        int n = rem >> 8, k = rem & 255;
        int h = n >> 5, j = n & 31;
        const float* wvb = Wv + ts[r] * 65536 + k * 256 + h * 32;
        const float* mb  = rel_msg + r * 8192 + h * 1024 + j;
        float s = 0.f;
        #pragma unroll 8
        for (int d = 0; d < 32; ++d) s += wvb[d] * mb[d * 32];
        WT[(5 + r) * 65536 + n * 256 + k] = f2bf(s);
    } else if (id < 10 * 65536) {
        int id2 = id - 8 * 65536;
        int t = id2 >> 16, rem = id2 & 65535;
        int n = rem >> 8, k = rem & 255;
        WT[(8 + t) * 65536 + n * 256 + k] = f2bf(Wa[t * 65536 + k * 256 + n]);
    } else if (id < 10 * 65536 + 2048) {
        int id2 = id - 10 * 65536;
        int z = id2 >> 8, c = id2 & 255;
        float v;
        if (z < 2) {
            v = bq[z * 256 + c];
        } else if (z < 5) {
            int r = z - 2, h = c >> 5, j = c & 31;
            const float* bkb = bk + ts[r] * 256 + h * 32;
            const float* ab  = rel_att + r * 8192 + h * 1024 + j;
            v = 0.f;
            for (int d = 0; d < 32; ++d) v += bkb[d] * ab[d * 32];
        } else {
            int r = z - 5, h = c >> 5, j = c & 31;
            const float* bvb = bv + ts[r] * 256 + h * 32;
            const float* mb  = rel_msg + r * 8192 + h * 1024 + j;
            v = 0.f;
            for (int d = 0; d < 32; ++d) v += bvb[d] * mb[d * 32];
        }
        ball[z * 256 + c] = v;
    }
}

// exclusive scan of bucket counts -> bbase[r][0..NBK], init bcur
__global__ __launch_bounds__(1024) void bscan_kernel(const int* __restrict__ bcnt,
                                                     int* __restrict__ bbase,
                                                     int* __restrict__ bcur)
{
    int r = blockIdx.x;
    int t = threadIdx.x, lane = t & 63, w = t >> 6;
    __shared__ int wsum[16];
    int x = (t < NBK) ? bcnt[r * NBK + t] : 0;
    int v = x;
    #pragma unroll
    for (int ofs = 1; ofs < 64; ofs <<= 1) {
        int y = __shfl_up(v, ofs);
        if (lane >= ofs) v += y;
    }
    if (lane == 63) wsum[w] = v;
    __syncthreads();
    if (t < 16) {
        int wv = wsum[t];
        #pragma unroll
        for (int ofs = 1; ofs < 16; ofs <<= 1) {
            int y = __shfl_up(wv, ofs);
            if (t >= ofs) wv += y;
        }
        wsum[t] = wv;
    }
    __syncthreads();
    int excl = (w > 0 ? wsum[w - 1] : 0) + v - x;
    if (t < NBK) { bbase[r * (NBK + 1) + t] = excl; bcur[r * NBK + t] = excl; }
    if (t == NBK - 1) bbase[r * (NBK + 1) + NBK] = excl + x;   // == EE
}

// P1: binned scatter. Per block: LDS hist -> contiguous per-bucket global
// reservation -> packed write (src<<6 | dst&63) into bucket region.
__global__ __launch_bounds__(256) void p1_kernel(const int* __restrict__ s0, const int* __restrict__ s1,
                                                 const int* __restrict__ s2,
                                                 const int* __restrict__ d0, const int* __restrict__ d1,
                                                 const int* __restrict__ d2,
                                                 int* __restrict__ bcur, unsigned int* __restrict__ srcS)
{
    int bb = blockIdx.x;
    int r = bb / NT1, tile = bb - r * NT1;
    const int* sp = r == 0 ? s0 : (r == 1 ? s1 : s2);
    const int* dp = r == 0 ? d0 : (r == 1 ? d1 : d2);
    __shared__ int hist[NBK];
    __shared__ int lbase[NBK];
    for (int i = threadIdx.x; i < NBK; i += 256) hist[i] = 0;
    __syncthreads();
    int base = tile * P1T;
    int lim = base + P1T; if (lim > EE) lim = EE;
    for (int i = base + threadIdx.x; i < lim; i += 256)
        atomicAdd(&hist[dp[i] >> 6], 1);
    __syncthreads();
    for (int i = threadIdx.x; i < NBK; i += 256)
        lbase[i] = hist[i] ? atomicAdd(&bcur[r * NBK + i], hist[i]) : 0;
    __syncthreads();
    unsigned int* out = srcS + (size_t)r * EE;
    for (int i = base + threadIdx.x; i < lim; i += 256) {
        int dv = dp[i];
        int bk = dv >> 6;
        int pos = atomicAdd(&lbase[bk], 1);
        out[pos] = ((unsigned)sp[i] << 6) | (unsigned)(dv & 63);
    }
}

// P2: one block per (relation, bucket). Group bucket's edges by dst fully in
// LDS; write srcs back in place (coalesced) + exact per-dst CSR offsets.
__global__ __launch_bounds__(256) void p2_kernel(const int* __restrict__ bbase,
                                                 unsigned int* __restrict__ srcS,
                                                 int* __restrict__ offs)
{
    int r = blockIdx.x / NBK, bk = blockIdx.x - r * NBK;
    int base = bbase[r * (NBK + 1) + bk];
    int n = bbase[r * (NBK + 1) + bk + 1] - base;
    unsigned int* seg = srcS + (size_t)r * EE + base;
    __shared__ unsigned int vals[BCAP];
    __shared__ unsigned int sorted[BCAP];
    __shared__ int hist[64], hcur[64];
    int t = threadIdx.x;
    if (t < 64) hist[t] = 0;
    __syncthreads();
    for (int i = t; i < n; i += 256) {
        unsigned int v = seg[i];
        vals[i] = v;
        atomicAdd(&hist[v & 63], 1);
    }
    __syncthreads();
    if (t < 64) {
        int x = hist[t], v = x;
        #pragma unroll
        for (int ofs = 1; ofs < 64; ofs <<= 1) {
            int y = __shfl_up(v, ofs);
            if (t >= ofs) v += y;
        }
        int excl = v - x;
        hcur[t] = excl;
        int d = bk * 64 + t;
        if (d < NN) offs[r * (NN + 1) + d] = base + excl;
    }
    if (bk == NBK - 1 && t == 64) offs[r * (NN + 1) + NN] = EE;
    __syncthreads();
    for (int i = t; i < n; i += 256) {
        unsigned int v = vals[i];
        int pos = atomicAdd(&hcur[v & 63], 1);
        sorted[pos] = v >> 6;
    }
    __syncthreads();
    for (int i = t; i < n; i += 256) seg[i] = sorted[i];
}

// ---------------------------------------------------------------------------
// GEMM body: [128 rows of A(f32->bf16)] x [128 cols of W(bf16 [n][k])],
// BK=64, 4 waves, XOR-swizzled LDS, bf16 out + bias.
// ---------------------------------------------------------------------------
__device__ __forceinline__ void gemm_body_f32(const float* __restrict__ A,
                                              const unsigned short* __restrict__ W,
                                              const float* __restrict__ bias,
                                              unsigned short* __restrict__ O,
                                              int mBase, int nBase)
{
    __shared__ __align__(16) unsigned short As[128 * 64];
    __shared__ __align__(16) unsigned short Bs[128 * 64];

    int tid = threadIdx.x;
    int lane = tid & 63, wid = tid >> 6;
    int warpM = wid >> 1, warpN = wid & 1;

    f32x4 acc[4][4];
    #pragma unroll
    for (int i = 0; i < 4; ++i)
        #pragma unroll
        for (int j = 0; j < 4; ++j) acc[i][j] = (f32x4){0.f, 0.f, 0.f, 0.f};

    for (int kt = 0; kt < 4; ++kt) {
        int k0 = kt * 64;
        __syncthreads();
        #pragma unroll
        for (int i = 0; i < 4; ++i) {
            int c = tid + i * 256;
            int row = c >> 3, cc = c & 7;
            int gr = mBase + row; if (gr > NN - 1) gr = NN - 1;
            const float* ap = A + (size_t)gr * CC + k0 + cc * 8;
            f32x4 lo = *(const f32x4*)ap;
            f32x4 hi = *(const f32x4*)(ap + 4);
            u32x4 av;
            av[0] = (unsigned)f2bf(lo[0]) | ((unsigned)f2bf(lo[1]) << 16);
            av[1] = (unsigned)f2bf(lo[2]) | ((unsigned)f2bf(lo[3]) << 16);
            av[2] = (unsigned)f2bf(hi[0]) | ((unsigned)f2bf(hi[1]) << 16);
            av[3] = (unsigned)f2bf(hi[2]) | ((unsigned)f2bf(hi[3]) << 16);
            int sb = row * 128 + ((cc * 16) ^ ((row & 7) << 4));
            *(u32x4*)((char*)As + sb) = av;
            u32x4 bv = *(const u32x4*)(W + (nBase + row) * 256 + k0 + cc * 8);
            *(u32x4*)((char*)Bs + sb) = bv;
        }
        __syncthreads();
        #pragma unroll
        for (int kk = 0; kk < 2; ++kk) {
            bf16x8 af[4], bfr[4];
            int kb = kk * 64 + (lane >> 4) * 16;
            #pragma unroll
            for (int mi = 0; mi < 4; ++mi) {
                int row = warpM * 64 + mi * 16 + (lane & 15);
                int sb = row * 128 + (kb ^ ((row & 7) << 4));
                af[mi] = *(const bf16x8*)((const char*)As + sb);
            }
            #pragma unroll
            for (int ni = 0; ni < 4; ++ni) {
                int row = warpN * 64 + ni * 16 + (lane & 15);
                int sb = row * 128 + (kb ^ ((row & 7) << 4));
                bfr[ni] = *(const bf16x8*)((const char*)Bs + sb);
            }
            #pragma unroll
            for (int mi = 0; mi < 4; ++mi)
                #pragma unroll
                for (int ni = 0; ni < 4; ++ni)
                    acc[mi][ni] = __builtin_amdgcn_mfma_f32_16x16x32_bf16(af[mi], bfr[ni], acc[mi][ni], 0, 0, 0);
        }
    }

    #pragma unroll
    for (int mi = 0; mi < 4; ++mi) {
        #pragma unroll
        for (int ni = 0; ni < 4; ++ni) {
            int col = nBase + warpN * 64 + ni * 16 + (lane & 15);
            int row0 = mBase + warpM * 64 + mi * 16 + (lane >> 4) * 4;
            float b = bias[col];
            #pragma unroll
            for (int j = 0; j < 4; ++j) {
                int row = row0 + j;
                if (row < NN) O[(size_t)row * CC + col] = f2bf(acc[mi][ni][j] + b);
            }
        }
    }
}

// 8 production GEMM slots in one launch (grid.z = slot)
__global__ __launch_bounds__(256, 2)
void gemm8_kernel(const float* __restrict__ hA, const float* __restrict__ hB,
                  const unsigned short* __restrict__ WT, const float* __restrict__ ball,
                  unsigned short* __restrict__ Qb, unsigned short* __restrict__ Kb0,
                  unsigned short* __restrict__ Kb1, unsigned short* __restrict__ dob)
{
    int z = blockIdx.z;
    const float* A = (z == 1 || z == 3 || z == 6) ? hB : hA;
    unsigned short* O;
    if (z < 2)       O = Qb + (size_t)z * NS;
    else if (z == 2) O = Kb0;
    else if (z == 3) O = Kb1;
    else             O = dob + (size_t)(z - 4) * NS;
    gemm_body_f32(A, WT + z * 65536, ball + z * 256, O,
                  blockIdx.x * 128, blockIdx.y * 128);
}

// ---------------------------------------------------------------------------
// Output GEMM: A bf16, out f32 with skip-residual.
// ---------------------------------------------------------------------------
__global__ __launch_bounds__(256, 2)
void out_gemm_kernel(const unsigned short* __restrict__ A0, const unsigned short* __restrict__ A1,
                     const unsigned short* __restrict__ W0, const unsigned short* __restrict__ W1,
                     const float* __restrict__ b0, const float* __restrict__ b1,
                     float* __restrict__ OutF,
                     const float* __restrict__ hA, const float* __restrict__ hB,
                     const float* __restrict__ skip)
{
    int z = blockIdx.z;
    const unsigned short* A = z ? A1 : A0;
    const unsigned short* W = z ? W1 : W0;
    const float* bias = z ? b1 : b0;
    int mBase = blockIdx.x * 128;
    int nBase = blockIdx.y * 128;

    __shared__ __align__(16) unsigned short As[128 * 64];
    __shared__ __align__(16) unsigned short Bs[128 * 64];

    int tid = threadIdx.x;
    int lane = tid & 63, wid = tid >> 6;
    int warpM = wid >> 1, warpN = wid & 1;

    f32x4 acc[4][4];
    #pragma unroll
    for (int i = 0; i < 4; ++i)
        #pragma unroll
        for (int j = 0; j < 4; ++j) acc[i][j] = (f32x4){0.f, 0.f, 0.f, 0.f};

    for (int kt = 0; kt < 4; ++kt) {
        int k0 = kt * 64;
        __syncthreads();
        #pragma unroll
        for (int i = 0; i < 4; ++i) {
            int c = tid + i * 256;
            int row = c >> 3, cc = c & 7;
            int gr = mBase + row; if (gr > NN - 1) gr = NN - 1;
            u32x4 av = *(const u32x4*)(A + (size_t)gr * CC + k0 + cc * 8);
            int sb = row * 128 + ((cc * 16) ^ ((row & 7) << 4));
            *(u32x4*)((char*)As + sb) = av;
            u32x4 bv = *(const u32x4*)(W + (nBase + row) * 256 + k0 + cc * 8);
            *(u32x4*)((char*)Bs + sb) = bv;
        }
        __syncthreads();
        #pragma unroll
        for (int kk = 0; kk < 2; ++kk) {
            bf16x8 af[4], bfr[4];
            int kb = kk * 64 + (lane >> 4) * 16;
            #pragma unroll
            for (int mi = 0; mi < 4; ++mi) {
                int row = warpM * 64 + mi * 16 + (lane & 15);
                int sb = row * 128 + (kb ^ ((row & 7) << 4));
                af[mi] = *(const bf16x8*)((const char*)As + sb);
            }
            #pragma unroll
            for (int ni = 0; ni < 4; ++ni) {
                int row = warpN * 64 + ni * 16 + (lane & 15);
                int sb = row * 128 + (kb ^ ((row & 7) << 4));
                bfr[ni] = *(const bf16x8*)((const char*)Bs + sb);
            }
            #pragma unroll
            for (int mi = 0; mi < 4; ++mi)
                #pragma unroll
                for (int ni = 0; ni < 4; ++ni)
                    acc[mi][ni] = __builtin_amdgcn_mfma_f32_16x16x32_bf16(af[mi], bfr[ni], acc[mi][ni], 0, 0, 0);
        }
    }

    float alpha = 1.f / (1.f + __expf(-skip[z]));
    const float* hres = z ? hB : hA;

    #pragma unroll
    for (int mi = 0; mi < 4; ++mi) {
        #pragma unroll
        for (int ni = 0; ni < 4; ++ni) {
            int col = nBase + warpN * 64 + ni * 16 + (lane & 15);
            int row0 = mBase + warpM * 64 + mi * 16 + (lane >> 4) * 4;
            float b = bias[col];
            #pragma unroll
            for (int j = 0; j < 4; ++j) {
                int row = row0 + j;
                if (row < NN) {
                    float val = acc[mi][ni][j] + b;
                    float hv = hres[(size_t)row * CC + col];
                    OutF[(size_t)z * NS + (size_t)row * CC + col] = val * alpha + hv * (1.f - alpha);
                }
            }
        }
    }
}

// ---------------------------------------------------------------------------
// Edge aggregation, all relations in one launch. One wave per (dst, relgroup).
// ---------------------------------------------------------------------------
__device__ __forceinline__ void agg_pass(const unsigned short* __restrict__ K,
                                         const unsigned short* __restrict__ V,
                                         const int* __restrict__ srcS,
                                         int beg, int end, int lane,
                                         float q0, float q1, float q2, float q3, float ps,
                                         float& o0, float& o1, float& o2, float& o3)
{
    float m = -INFINITY, l = 0.f;
    float a0 = 0.f, a1 = 0.f, a2 = 0.f, a3 = 0.f;
    int n = end - beg;
    int idx = 0;
    if (n > 0) {
        int p = beg + lane;
        idx = srcS[p < end ? p : end - 1];
    }
    for (int j = 0; j < n; ++j) {
        if (j && (j & 63) == 0) {
            int p = beg + j + lane;
            idx = srcS[p < end ? p : end - 1];
        }
        int s = __shfl(idx, j & 63);
        u32x2 kv = *(const u32x2*)(K + (size_t)s * CC + lane * 4);
        u32x2 vv = *(const u32x2*)(V + (size_t)s * CC + lane * 4);
        float d = q0 * bf2f(kv[0] & 0xffffu) + q1 * bf2f(kv[0] >> 16)
                + q2 * bf2f(kv[1] & 0xffffu) + q3 * bf2f(kv[1] >> 16);
        d += __shfl_xor(d, 1);
        d += __shfl_xor(d, 2);
        d += __shfl_xor(d, 4);
        float sc = d * ps;
        float mn = fmaxf(m, sc);
        float cs = __expf(m - mn);
        float p  = __expf(sc - mn);
        l = l * cs + p;
        a0 = a0 * cs + p * bf2f(vv[0] & 0xffffu);
        a1 = a1 * cs + p * bf2f(vv[0] >> 16);
        a2 = a2 * cs + p * bf2f(vv[1] & 0xffffu);
        a3 = a3 * cs + p * bf2f(vv[1] >> 16);
        m = mn;
    }
    float inv = (l > 0.f) ? 1.f / l : 0.f;
    o0 = a0 * inv; o1 = a1 * inv; o2 = a2 * inv; o3 = a3 * inv;
}

__global__ __launch_bounds__(256)
void agg_all_kernel(const unsigned short* __restrict__ Q0, const unsigned short* __restrict__ Q1,
                    const unsigned short* __restrict__ K0, const unsigned short* __restrict__ V0,
                    const unsigned short* __restrict__ K1, const unsigned short* __restrict__ V1,
                    const unsigned short* __restrict__ K2, const unsigned short* __restrict__ V2,
                    const int* __restrict__ offs, const int* __restrict__ srcS,
                    const float* __restrict__ rel_pri,
                    unsigned short* __restrict__ TbA, unsigned short* __restrict__ TbB)
{
    int w = (blockIdx.x * 256 + threadIdx.x) >> 6;
    int lane = threadIdx.x & 63;
    int h = lane >> 3;
    const float rs = 0.17677669529663687f;  // 1/sqrt(32)

    if (w < NN) {
        int d = w;
        u32x2 qv = *(const u32x2*)(Q1 + (size_t)d * CC + lane * 4);
        float q0 = bf2f(qv[0] & 0xffffu), q1 = bf2f(qv[0] >> 16);
        float q2 = bf2f(qv[1] & 0xffffu), q3 = bf2f(qv[1] >> 16);
        float x0, x1, x2, x3, y0, y1, y2, y3;
        agg_pass(K0, V0, srcS, offs[d], offs[d + 1], lane,
                 q0, q1, q2, q3, rel_pri[h] * rs, x0, x1, x2, x3);
        const int* off2 = offs + 2 * (NN + 1);
        agg_pass(K2, V2, srcS + 2 * EE, off2[d], off2[d + 1], lane,
                 q0, q1, q2, q3, rel_pri[16 + h] * rs, y0, y1, y2, y3);
        unsigned short* out = TbB + (size_t)d * CC + lane * 4;
        u32x2 o;
        o[0] = (unsigned)f2bf((x0 + y0) * 0.5f) | ((unsigned)f2bf((x1 + y1) * 0.5f) << 16);
        o[1] = (unsigned)f2bf((x2 + y2) * 0.5f) | ((unsigned)f2bf((x3 + y3) * 0.5f) << 16);
        *(u32x2*)out = o;
    } else if (w < 2 * NN) {
        int d = w - NN;
        u32x2 qv = *(const u32x2*)(Q0 + (size_t)d * CC + lane * 4);
        float q0 = bf2f(qv[0] & 0xffffu), q1 = bf2f(qv[0] >> 16);
        float q2 = bf2f(qv[1] & 0xffffu), q3 = bf2f(qv[1] >> 16);
        float x0, x1, x2, x3;
        const int* off1 = offs + (NN + 1);
        agg_pass(K1, V1, srcS + EE, off1[d], off1[d + 1], lane,
                 q0, q1, q2, q3, rel_pri[8 + h] * rs, x0, x1, x2, x3);
        unsigned short* out = TbA + (size_t)d * CC + lane * 4;
        u32x2 o;
        o[0] = (unsigned)f2bf(x0) | ((unsigned)f2bf(x1) << 16);
        o[1] = (unsigned)f2bf(x2) | ((unsigned)f2bf(x3) << 16);
        *(u32x2*)out = o;
    }
}

// ---------------------------------------------------------------------------
extern "C" void kernel_launch(void* const* d_in, const int* in_sizes, int n_in,
                              void* d_out, int out_size, void* d_ws, size_t ws_size,
                              hipStream_t stream)
{
    const float* hA = (const float*)d_in[0];
    const float* hB = (const float*)d_in[1];
    const int* src0 = (const int*)d_in[2];
    const int* dst0 = (const int*)d_in[3];
    const int* src1 = (const int*)d_in[4];
    const int* dst1 = (const int*)d_in[5];
    const int* src2 = (const int*)d_in[6];
    const int* dst2 = (const int*)d_in[7];
    const float* Wk = (const float*)d_in[8];
    const float* bk = (const float*)d_in[9];
    const float* Wq = (const float*)d_in[10];
    const float* bq = (const float*)d_in[11];
    const float* Wv = (const float*)d_in[12];
    const float* bv = (const float*)d_in[13];
    const float* Wa = (const float*)d_in[14];
    const float* ba = (const float*)d_in[15];
    const float* rel_att = (const float*)d_in[16];
    const float* rel_msg = (const float*)d_in[17];
    const float* rel_pri = (const float*)d_in[18];
    const float* skip = (const float*)d_in[19];

    char* w = (char*)d_ws;
    auto alloc = [&](size_t bytes) {
        char* p = w;
        w += (bytes + 255) & ~(size_t)255;
        return p;
    };
    // ws total ~165 MB (within known-good budget)
    unsigned short* WT  = (unsigned short*)alloc((size_t)10 * 65536 * 2);
    float* ball         = (float*)alloc((size_t)8 * 256 * 4);
    unsigned short* Qb  = (unsigned short*)alloc((size_t)2 * NS * 2);  // Q0,Q1
    unsigned short* Kb0 = (unsigned short*)alloc((size_t)NS * 2);      // K r0
    unsigned short* Kb1 = (unsigned short*)alloc((size_t)NS * 2);      // K r1
    unsigned short* Tb  = (unsigned short*)alloc((size_t)2 * NS * 2);  // t per type
    int* offs           = (int*)alloc((size_t)3 * (NN + 1) * 4);
    int* srcS           = (int*)alloc((size_t)3 * EE * 4);
    int* bcnt           = (int*)alloc((size_t)3 * NBK * 4);
    int* bbase          = (int*)alloc((size_t)3 * (NBK + 1) * 4);
    int* bcur           = (int*)alloc((size_t)3 * NBK * 4);

    // 4 bf16 QKV slots live in d_out (102.4 MB, dead until final GEMM)
    unsigned short* dob = (unsigned short*)d_out;

    hipMemsetAsync(bcnt, 0, (size_t)3 * NBK * 4, stream);

    // prep weights + P0 bucket histogram (fused; disjoint block ranges)
    setup_kernel<<<2568 + 3 * NT1, 256, 0, stream>>>(Wk, bk, Wq, bq, Wv, bv, Wa,
                                                     rel_att, rel_msg, WT, ball,
                                                     dst0, dst1, dst2, bcnt);
    bscan_kernel<<<3, 1024, 0, stream>>>(bcnt, bbase, bcur);
    p1_kernel<<<3 * NT1, 256, 0, stream>>>(src0, src1, src2, dst0, dst1, dst2,
                                           bcur, (unsigned int*)srcS);
    p2_kernel<<<3 * NBK, 256, 0, stream>>>(bbase, (unsigned int*)srcS, offs);

    // all 8 production GEMMs (Q0,Q1,K0,K1 in ws; K2,V0,V1,V2 in d_out)
    gemm8_kernel<<<dim3(391, 2, 8), 256, 0, stream>>>(hA, hB, WT, ball,
                                                      Qb, Kb0, Kb1, dob);

    // all 3 relations' aggregation in one launch
    agg_all_kernel<<<25000, 256, 0, stream>>>(Qb, Qb + NS, Kb0, dob + 1 * (size_t)NS,
                                              Kb1, dob + 2 * (size_t)NS,
                                              dob + 0 * (size_t)NS, dob + 3 * (size_t)NS,
                                              offs, srcS, rel_pri, Tb, Tb + NS);

    // output GEMM overwrites d_out (reads only Tb/hA/hB/WT)
    out_gemm_kernel<<<dim3(391, 2, 2), 256, 0, stream>>>(
        Tb, Tb + NS, WT + 8 * 65536, WT + 9 * 65536, ba, ba + 256,
        (float*)d_out, hA, hB, skip);
}

// Round 7
// 710.375 us; speedup vs baseline: 1.4674x; 1.0021x over previous
//
#include <hip/hip_runtime.h>
#include <math.h>

#define NN 50000
#define EE 800000
#define CC 256
#define NS (NN * CC)
#define NBK 782        // dst buckets per relation (64 dsts each; 782*64 >= NN)
#define BCAP 2048      // LDS capacity per bucket in P2 (mean 1023, +32 sigma)
#define P1T 2048       // edges per P0/P1 tile
#define NT1 391        // tiles per relation = ceil(EE / P1T)

typedef __attribute__((ext_vector_type(4))) float f32x4;
typedef __attribute__((ext_vector_type(8))) short bf16x8;
typedef __attribute__((ext_vector_type(4))) unsigned int u32x4;
typedef __attribute__((ext_vector_type(2))) unsigned int u32x2;

__device__ __forceinline__ float bf2f(unsigned int u) {
    union { unsigned int i; float f; } c; c.i = u << 16; return c.f;
}
__device__ __forceinline__ unsigned short f2bf(float f) {
    union { float f; unsigned int i; } c; c.f = f;
    unsigned int u = c.i;
    u += 0x7fffu + ((u >> 16) & 1u);
    return (unsigned short)(u >> 16);
}

// ---------------------------------------------------------------------------
// setup: prep weights (blocks [0,2568)) + P0 bucket histogram (blocks >= 2568).
// WT slots: 0-1 WqT(t), 2-4 WckT(r), 5-7 WcvT(r), 8-9 WaT(t)
// ball slots: 0-1 bq(t), 2-4 folded bk(r), 5-7 folded bv(r)
// bcnt zeroed by hipMemsetAsync before this kernel.
// ---------------------------------------------------------------------------
__global__ void setup_kernel(const float* __restrict__ Wk, const float* __restrict__ bk,
                             const float* __restrict__ Wq, const float* __restrict__ bq,
                             const float* __restrict__ Wv, const float* __restrict__ bv,
                             const float* __restrict__ Wa,
                             const float* __restrict__ rel_att, const float* __restrict__ rel_msg,
                             unsigned short* __restrict__ WT, float* __restrict__ ball,
                             const int* __restrict__ d0, const int* __restrict__ d1,
                             const int* __restrict__ d2, int* __restrict__ bcnt)
{
    int b = blockIdx.x;
    const int ts[3] = {0, 1, 0};  // source node type per relation
    if (b >= 2568) {
        // P0: bucket histogram
        int bb = b - 2568;               // 0 .. 3*NT1-1
        int r = bb / NT1, tile = bb - r * NT1;
        const int* dp = r == 0 ? d0 : (r == 1 ? d1 : d2);
        __shared__ int hist[NBK];
        for (int i = threadIdx.x; i < NBK; i += 256) hist[i] = 0;
        __syncthreads();
        int base = tile * P1T;
        int lim = base + P1T; if (lim > EE) lim = EE;
        for (int i = base + threadIdx.x; i < lim; i += 256)
            atomicAdd(&hist[dp[i] >> 6], 1);
        __syncthreads();
        for (int i = threadIdx.x; i < NBK; i += 256)
            if (hist[i]) atomicAdd(&bcnt[r * NBK + i], hist[i]);
        return;
    }
    int id = b * 256 + threadIdx.x;
    if (id < 2 * 65536) {
        int t = id >> 16, rem = id & 65535;
        int n = rem >> 8, k = rem & 255;
        WT[t * 65536 + n * 256 + k] = f2bf(Wq[t * 65536 + k * 256 + n]);
    } else if (id < 5 * 65536) {
        int id2 = id - 2 * 65536;
        int r = id2 >> 16, rem = id2 & 65535;
        int n = rem >> 8, k = rem & 255;
        int h = n >> 5, j = n & 31;
        const float* wkb = Wk + ts[r] * 65536 + k * 256 + h * 32;
        const float* ab  = rel_att + r * 8192 + h * 1024 + j;
        float s = 0.f;
        #pragma unroll 8
        for (int d = 0; d < 32; ++d) s += wkb[d] * ab[d * 32];
        WT[(2 + r) * 65536 + n * 256 + k] = f2bf(s);
    } else if (id < 8 * 65536) {
        int id2 = id - 5 * 65536;
        int r = id2 >> 16, rem = id2 & 65535;
        int n = rem >> 8, k = rem & 255;
        int h = n >> 5, j = n & 31;
        const float* wvb = Wv + ts[r] * 65536 + k * 256 + h * 32;
        const float* mb  = rel_msg + r * 8192 + h * 1024 + j;
        float s = 0.f;
        #pragma unroll 8
        for (int d = 0; d < 32; ++d) s += wvb[d] * mb[d * 32];
        WT[(5 + r) * 65536 + n * 256 + k] = f2bf(s);
    } else if (id < 10 * 65536) {
        int id2 = id - 8 * 65536;
        int t = id2 >> 16, rem = id2 & 65535;
        int n = rem >> 8, k = rem & 255;
        WT[(8 + t) * 65536 + n * 256 + k] = f2bf(Wa[t * 65536 + k * 256 + n]);
    } else if (id < 10 * 65536 + 2048) {
        int id2 = id - 10 * 65536;
        int z = id2 >> 8, c = id2 & 255;
        float v;
        if (z < 2) {
            v = bq[z * 256 + c];
        } else if (z < 5) {
            int r = z - 2, h = c >> 5, j = c & 31;
            const float* bkb = bk + ts[r] * 256 + h * 32;
            const float* ab  = rel_att + r * 8192 + h * 1024 + j;
            v = 0.f;
            for (int d = 0; d < 32; ++d) v += bkb[d] * ab[d * 32];
        } else {
            int r = z - 5, h = c >> 5, j = c & 31;
            const float* bvb = bv + ts[r] * 256 + h * 32;
            const float* mb  = rel_msg + r * 8192 + h * 1024 + j;
            v = 0.f;
            for (int d = 0; d < 32; ++d) v += bvb[d] * mb[d * 32];
        }
        ball[z * 256 + c] = v;
    }
}

// exclusive scan of bucket counts -> bbase[r][0..NBK], init bcur
__global__ __launch_bounds__(1024) void bscan_kernel(const int* __restrict__ bcnt,
                                                     int* __restrict__ bbase,
                                                     int* __restrict__ bcur)
{
    int r = blockIdx.x;
    int t = threadIdx.x, lane = t & 63, w = t >> 6;
    __shared__ int wsum[16];
    int x = (t < NBK) ? bcnt[r * NBK + t] : 0;
    int v = x;
    #pragma unroll
    for (int ofs = 1; ofs < 64; ofs <<= 1) {
        int y = __shfl_up(v, ofs);
        if (lane >= ofs) v += y;
    }
    if (lane == 63) wsum[w] = v;
    __syncthreads();
    if (t < 16) {
        int wv = wsum[t];
        #pragma unroll
        for (int ofs = 1; ofs < 16; ofs <<= 1) {
            int y = __shfl_up(wv, ofs);
            if (t >= ofs) wv += y;
        }
        wsum[t] = wv;
    }
    __syncthreads();
    int excl = (w > 0 ? wsum[w - 1] : 0) + v - x;
    if (t < NBK) { bbase[r * (NBK + 1) + t] = excl; bcur[r * NBK + t] = excl; }
    if (t == NBK - 1) bbase[r * (NBK + 1) + NBK] = excl + x;   // == EE
}

// P1: binned scatter. Per block: LDS hist -> contiguous per-bucket global
// reservation -> packed write (src<<6 | dst&63) into bucket region.
__global__ __launch_bounds__(256) void p1_kernel(const int* __restrict__ s0, const int* __restrict__ s1,
                                                 const int* __restrict__ s2,
                                                 const int* __restrict__ d0, const int* __restrict__ d1,
                                                 const int* __restrict__ d2,
                                                 int* __restrict__ bcur, unsigned int* __restrict__ srcS)
{
    int bb = blockIdx.x;
    int r = bb / NT1, tile = bb - r * NT1;
    const int* sp = r == 0 ? s0 : (r == 1 ? s1 : s2);
    const int* dp = r == 0 ? d0 : (r == 1 ? d1 : d2);
    __shared__ int hist[NBK];
    __shared__ int lbase[NBK];
    for (int i = threadIdx.x; i < NBK; i += 256) hist[i] = 0;
    __syncthreads();
    int base = tile * P1T;
    int lim = base + P1T; if (lim > EE) lim = EE;
    for (int i = base + threadIdx.x; i < lim; i += 256)
        atomicAdd(&hist[dp[i] >> 6], 1);
    __syncthreads();
    for (int i = threadIdx.x; i < NBK; i += 256)
        lbase[i] = hist[i] ? atomicAdd(&bcur[r * NBK + i], hist[i]) : 0;
    __syncthreads();
    unsigned int* out = srcS + (size_t)r * EE;
    for (int i = base + threadIdx.x; i < lim; i += 256) {
        int dv = dp[i];
        int bk = dv >> 6;
        int pos = atomicAdd(&lbase[bk], 1);
        out[pos] = ((unsigned)sp[i] << 6) | (unsigned)(dv & 63);
    }
}

// P2: one block per (relation, bucket). Group bucket's edges by dst fully in
// LDS; write srcs back in place (coalesced) + exact per-dst CSR offsets.
__global__ __launch_bounds__(256) void p2_kernel(const int* __restrict__ bbase,
                                                 unsigned int* __restrict__ srcS,
                                                 int* __restrict__ offs)
{
    int r = blockIdx.x / NBK, bk = blockIdx.x - r * NBK;
    int base = bbase[r * (NBK + 1) + bk];
    int n = bbase[r * (NBK + 1) + bk + 1] - base;
    unsigned int* seg = srcS + (size_t)r * EE + base;
    __shared__ unsigned int vals[BCAP];
    __shared__ unsigned int sorted[BCAP];
    __shared__ int hist[64], hcur[64];
    int t = threadIdx.x;
    if (t < 64) hist[t] = 0;
    __syncthreads();
    for (int i = t; i < n; i += 256) {
        unsigned int v = seg[i];
        vals[i] = v;
        atomicAdd(&hist[v & 63], 1);
    }
    __syncthreads();
    if (t < 64) {
        int x = hist[t], v = x;
        #pragma unroll
        for (int ofs = 1; ofs < 64; ofs <<= 1) {
            int y = __shfl_up(v, ofs);
            if (t >= ofs) v += y;
        }
        int excl = v - x;
        hcur[t] = excl;
        int d = bk * 64 + t;
        if (d < NN) offs[r * (NN + 1) + d] = base + excl;
    }
    if (bk == NBK - 1 && t == 64) offs[r * (NN + 1) + NN] = EE;
    __syncthreads();
    for (int i = t; i < n; i += 256) {
        unsigned int v = vals[i];
        int pos = atomicAdd(&hcur[v & 63], 1);
        sorted[pos] = v >> 6;
    }
    __syncthreads();
    for (int i = t; i < n; i += 256) seg[i] = sorted[i];
}

// ---------------------------------------------------------------------------
// GEMM body: [128 rows of A(f32->bf16)] x [128 cols of W(bf16 [n][k])],
// BK=64, 4 waves, XOR-swizzled LDS, bf16 out + bias.
// ---------------------------------------------------------------------------
__device__ __forceinline__ void gemm_body_f32(const float* __restrict__ A,
                                              const unsigned short* __restrict__ W,
                                              const float* __restrict__ bias,
                                              unsigned short* __restrict__ O,
                                              int mBase, int nBase)
{
    __shared__ __align__(16) unsigned short As[128 * 64];
    __shared__ __align__(16) unsigned short Bs[128 * 64];

    int tid = threadIdx.x;
    int lane = tid & 63, wid = tid >> 6;
    int warpM = wid >> 1, warpN = wid & 1;

    f32x4 acc[4][4];
    #pragma unroll
    for (int i = 0; i < 4; ++i)
        #pragma unroll
        for (int j = 0; j < 4; ++j) acc[i][j] = (f32x4){0.f, 0.f, 0.f, 0.f};

    for (int kt = 0; kt < 4; ++kt) {
        int k0 = kt * 64;
        __syncthreads();
        #pragma unroll
        for (int i = 0; i < 4; ++i) {
            int c = tid + i * 256;
            int row = c >> 3, cc = c & 7;
            int gr = mBase + row; if (gr > NN - 1) gr = NN - 1;
            const float* ap = A + (size_t)gr * CC + k0 + cc * 8;
            f32x4 lo = *(const f32x4*)ap;
            f32x4 hi = *(const f32x4*)(ap + 4);
            u32x4 av;
            av[0] = (unsigned)f2bf(lo[0]) | ((unsigned)f2bf(lo[1]) << 16);
            av[1] = (unsigned)f2bf(lo[2]) | ((unsigned)f2bf(lo[3]) << 16);
            av[2] = (unsigned)f2bf(hi[0]) | ((unsigned)f2bf(hi[1]) << 16);
            av[3] = (unsigned)f2bf(hi[2]) | ((unsigned)f2bf(hi[3]) << 16);
            int sb = row * 128 + ((cc * 16) ^ ((row & 7) << 4));
            *(u32x4*)((char*)As + sb) = av;
            u32x4 bv = *(const u32x4*)(W + (nBase + row) * 256 + k0 + cc * 8);
            *(u32x4*)((char*)Bs + sb) = bv;
        }
        __syncthreads();
        #pragma unroll
        for (int kk = 0; kk < 2; ++kk) {
            bf16x8 af[4], bfr[4];
            int kb = kk * 64 + (lane >> 4) * 16;
            #pragma unroll
            for (int mi = 0; mi < 4; ++mi) {
                int row = warpM * 64 + mi * 16 + (lane & 15);
                int sb = row * 128 + (kb ^ ((row & 7) << 4));
                af[mi] = *(const bf16x8*)((const char*)As + sb);
            }
            #pragma unroll
            for (int ni = 0; ni < 4; ++ni) {
                int row = warpN * 64 + ni * 16 + (lane & 15);
                int sb = row * 128 + (kb ^ ((row & 7) << 4));
                bfr[ni] = *(const bf16x8*)((const char*)Bs + sb);
            }
            #pragma unroll
            for (int mi = 0; mi < 4; ++mi)
                #pragma unroll
                for (int ni = 0; ni < 4; ++ni)
                    acc[mi][ni] = __builtin_amdgcn_mfma_f32_16x16x32_bf16(af[mi], bfr[ni], acc[mi][ni], 0, 0, 0);
        }
    }

    #pragma unroll
    for (int mi = 0; mi < 4; ++mi) {
        #pragma unroll
        for (int ni = 0; ni < 4; ++ni) {
            int col = nBase + warpN * 64 + ni * 16 + (lane & 15);
            int row0 = mBase + warpM * 64 + mi * 16 + (lane >> 4) * 4;
            float b = bias[col];
            #pragma unroll
            for (int j = 0; j < 4; ++j) {
                int row = row0 + j;
                if (row < NN) O[(size_t)row * CC + col] = f2bf(acc[mi][ni][j] + b);
            }
        }
    }
}

// 8 production GEMM slots in one launch (grid.z = slot); outputs bf16
__global__ __launch_bounds__(256, 2)
void gemm8_kernel(const float* __restrict__ hA, const float* __restrict__ hB,
                  const unsigned short* __restrict__ WT, const float* __restrict__ ball,
                  unsigned short* __restrict__ Qb, unsigned short* __restrict__ Kb0,
                  unsigned short* __restrict__ Kb1, unsigned short* __restrict__ dob)
{
    int z = blockIdx.z;
    const float* A = (z == 1 || z == 3 || z == 6) ? hB : hA;
    unsigned short* O;
    if (z < 2)       O = Qb + (size_t)z * NS;
    else if (z == 2) O = Kb0;
    else if (z == 3) O = Kb1;
    else             O = dob + (size_t)(z - 4) * NS;
    gemm_body_f32(A, WT + z * 65536, ball + z * 256, O,
                  blockIdx.x * 128, blockIdx.y * 128);
}

// ---------------------------------------------------------------------------
// Output GEMM: A bf16, out f32 with skip-residual.
// ---------------------------------------------------------------------------
__global__ __launch_bounds__(256, 2)
void out_gemm_kernel(const unsigned short* __restrict__ A0, const unsigned short* __restrict__ A1,
                     const unsigned short* __restrict__ W0, const unsigned short* __restrict__ W1,
                     const float* __restrict__ b0, const float* __restrict__ b1,
                     float* __restrict__ OutF,
                     const float* __restrict__ hA, const float* __restrict__ hB,
                     const float* __restrict__ skip)
{
    int z = blockIdx.z;
    const unsigned short* A = z ? A1 : A0;
    const unsigned short* W = z ? W1 : W0;
    const float* bias = z ? b1 : b0;
    int mBase = blockIdx.x * 128;
    int nBase = blockIdx.y * 128;

    __shared__ __align__(16) unsigned short As[128 * 64];
    __shared__ __align__(16) unsigned short Bs[128 * 64];

    int tid = threadIdx.x;
    int lane = tid & 63, wid = tid >> 6;
    int warpM = wid >> 1, warpN = wid & 1;

    f32x4 acc[4][4];
    #pragma unroll
    for (int i = 0; i < 4; ++i)
        #pragma unroll
        for (int j = 0; j < 4; ++j) acc[i][j] = (f32x4){0.f, 0.f, 0.f, 0.f};

    for (int kt = 0; kt < 4; ++kt) {
        int k0 = kt * 64;
        __syncthreads();
        #pragma unroll
        for (int i = 0; i < 4; ++i) {
            int c = tid + i * 256;
            int row = c >> 3, cc = c & 7;
            int gr = mBase + row; if (gr > NN - 1) gr = NN - 1;
            u32x4 av = *(const u32x4*)(A + (size_t)gr * CC + k0 + cc * 8);
            int sb = row * 128 + ((cc * 16) ^ ((row & 7) << 4));
            *(u32x4*)((char*)As + sb) = av;
            u32x4 bv = *(const u32x4*)(W + (nBase + row) * 256 + k0 + cc * 8);
            *(u32x4*)((char*)Bs + sb) = bv;
        }
        __syncthreads();
        #pragma unroll
        for (int kk = 0; kk < 2; ++kk) {
            bf16x8 af[4], bfr[4];
            int kb = kk * 64 + (lane >> 4) * 16;
            #pragma unroll
            for (int mi = 0; mi < 4; ++mi) {
                int row = warpM * 64 + mi * 16 + (lane & 15);
                int sb = row * 128 + (kb ^ ((row & 7) << 4));
                af[mi] = *(const bf16x8*)((const char*)As + sb);
            }
            #pragma unroll
            for (int ni = 0; ni < 4; ++ni) {
                int row = warpN * 64 + ni * 16 + (lane & 15);
                int sb = row * 128 + (kb ^ ((row & 7) << 4));
                bfr[ni] = *(const bf16x8*)((const char*)Bs + sb);
            }
            #pragma unroll
            for (int mi = 0; mi < 4; ++mi)
                #pragma unroll
                for (int ni = 0; ni < 4; ++ni)
                    acc[mi][ni] = __builtin_amdgcn_mfma_f32_16x16x32_bf16(af[mi], bfr[ni], acc[mi][ni], 0, 0, 0);
        }
    }

    float alpha = 1.f / (1.f + __expf(-skip[z]));
    const float* hres = z ? hB : hA;

    #pragma unroll
    for (int mi = 0; mi < 4; ++mi) {
        #pragma unroll
        for (int ni = 0; ni < 4; ++ni) {
            int col = nBase + warpN * 64 + ni * 16 + (lane & 15);
            int row0 = mBase + warpM * 64 + mi * 16 + (lane >> 4) * 4;
            float b = bias[col];
            #pragma unroll
            for (int j = 0; j < 4; ++j) {
                int row = row0 + j;
                if (row < NN) {
                    float val = acc[mi][ni][j] + b;
                    float hv = hres[(size_t)row * CC + col];
                    OutF[(size_t)z * NS + (size_t)row * CC + col] = val * alpha + hv * (1.f - alpha);
                }
            }
        }
    }
}

// ---------------------------------------------------------------------------
// Edge aggregation, bf16 Q/K/V (round-4-proven path). No online max (scores
// O(0.1) bounded -> exp safe, softmax shift-invariance makes it exact).
// One-edge-ahead prefetch of K/V rows.
// ---------------------------------------------------------------------------
__device__ __forceinline__ void agg_pass(const unsigned short* __restrict__ K,
                                         const unsigned short* __restrict__ V,
                                         const int* __restrict__ srcS,
                                         int beg, int end, int lane,
                                         float q0, float q1, float q2, float q3, float ps,
                                         float& o0, float& o1, float& o2, float& o3)
{
    float l = 0.f;
    float a0 = 0.f, a1 = 0.f, a2 = 0.f, a3 = 0.f;
    int n = end - beg;
    if (n > 0) {
        int p0 = beg + lane;
        int idx = srcS[p0 < end ? p0 : end - 1];
        int s = __shfl(idx, 0);
        u32x2 kv = *(const u32x2*)(K + (size_t)s * CC + lane * 4);
        u32x2 vv = *(const u32x2*)(V + (size_t)s * CC + lane * 4);
        for (int j = 0; j < n; ++j) {
            u32x2 kc = kv, vc = vv;
            int jn = j + 1;
            if (jn < n) {
                if ((jn & 63) == 0) {
                    int p = beg + jn + lane;
                    idx = srcS[p < end ? p : end - 1];
                }
                int sn = __shfl(idx, jn & 63);
                kv = *(const u32x2*)(K + (size_t)sn * CC + lane * 4);
                vv = *(const u32x2*)(V + (size_t)sn * CC + lane * 4);
            }
            float d = q0 * bf2f(kc[0] & 0xffffu) + q1 * bf2f(kc[0] >> 16)
                    + q2 * bf2f(kc[1] & 0xffffu) + q3 * bf2f(kc[1] >> 16);
            d += __shfl_xor(d, 1);
            d += __shfl_xor(d, 2);
            d += __shfl_xor(d, 4);
            float pw = __expf(d * ps);
            l += pw;
            a0 += pw * bf2f(vc[0] & 0xffffu);
            a1 += pw * bf2f(vc[0] >> 16);
            a2 += pw * bf2f(vc[1] & 0xffffu);
            a3 += pw * bf2f(vc[1] >> 16);
        }
    }
    float inv = (l > 0.f) ? 1.f / l : 0.f;
    o0 = a0 * inv; o1 = a1 * inv; o2 = a2 * inv; o3 = a3 * inv;
}

__global__ __launch_bounds__(256)
void agg_all_kernel(const unsigned short* __restrict__ Q0, const unsigned short* __restrict__ Q1,
                    const unsigned short* __restrict__ K0, const unsigned short* __restrict__ V0,
                    const unsigned short* __restrict__ K1, const unsigned short* __restrict__ V1,
                    const unsigned short* __restrict__ K2, const unsigned short* __restrict__ V2,
                    const int* __restrict__ offs, const int* __restrict__ srcS,
                    const float* __restrict__ rel_pri,
                    unsigned short* __restrict__ TbA, unsigned short* __restrict__ TbB)
{
    int w = (blockIdx.x * 256 + threadIdx.x) >> 6;
    int lane = threadIdx.x & 63;
    int h = lane >> 3;
    const float rs = 0.17677669529663687f;  // 1/sqrt(32)

    if (w < NN) {
        int d = w;
        u32x2 qv = *(const u32x2*)(Q1 + (size_t)d * CC + lane * 4);
        float q0 = bf2f(qv[0] & 0xffffu), q1 = bf2f(qv[0] >> 16);
        float q2 = bf2f(qv[1] & 0xffffu), q3 = bf2f(qv[1] >> 16);
        float x0, x1, x2, x3, y0, y1, y2, y3;
        agg_pass(K0, V0, srcS, offs[d], offs[d + 1], lane,
                 q0, q1, q2, q3, rel_pri[h] * rs, x0, x1, x2, x3);
        const int* off2 = offs + 2 * (NN + 1);
        agg_pass(K2, V2, srcS + 2 * EE, off2[d], off2[d + 1], lane,
                 q0, q1, q2, q3, rel_pri[16 + h] * rs, y0, y1, y2, y3);
        unsigned short* out = TbB + (size_t)d * CC + lane * 4;
        u32x2 o;
        o[0] = (unsigned)f2bf((x0 + y0) * 0.5f) | ((unsigned)f2bf((x1 + y1) * 0.5f) << 16);
        o[1] = (unsigned)f2bf((x2 + y2) * 0.5f) | ((unsigned)f2bf((x3 + y3) * 0.5f) << 16);
        *(u32x2*)out = o;
    } else if (w < 2 * NN) {
        int d = w - NN;
        u32x2 qv = *(const u32x2*)(Q0 + (size_t)d * CC + lane * 4);
        float q0 = bf2f(qv[0] & 0xffffu), q1 = bf2f(qv[0] >> 16);
        float q2 = bf2f(qv[1] & 0xffffu), q3 = bf2f(qv[1] >> 16);
        float x0, x1, x2, x3;
        const int* off1 = offs + (NN + 1);
        agg_pass(K1, V1, srcS + EE, off1[d], off1[d + 1], lane,
                 q0, q1, q2, q3, rel_pri[8 + h] * rs, x0, x1, x2, x3);
        unsigned short* out = TbA + (size_t)d * CC + lane * 4;
        u32x2 o;
        o[0] = (unsigned)f2bf(x0) | ((unsigned)f2bf(x1) << 16);
        o[1] = (unsigned)f2bf(x2) | ((unsigned)f2bf(x3) << 16);
        *(u32x2*)out = o;
    }
}

// ---------------------------------------------------------------------------
extern "C" void kernel_launch(void* const* d_in, const int* in_sizes, int n_in,
                              void* d_out, int out_size, void* d_ws, size_t ws_size,
                              hipStream_t stream)
{
    const float* hA = (const float*)d_in[0];
    const float* hB = (const float*)d_in[1];
    const int* src0 = (const int*)d_in[2];
    const int* dst0 = (const int*)d_in[3];
    const int* src1 = (const int*)d_in[4];
    const int* dst1 = (const int*)d_in[5];
    const int* src2 = (const int*)d_in[6];
    const int* dst2 = (const int*)d_in[7];
    const float* Wk = (const float*)d_in[8];
    const float* bk = (const float*)d_in[9];
    const float* Wq = (const float*)d_in[10];
    const float* bq = (const float*)d_in[11];
    const float* Wv = (const float*)d_in[12];
    const float* bv = (const float*)d_in[13];
    const float* Wa = (const float*)d_in[14];
    const float* ba = (const float*)d_in[15];
    const float* rel_att = (const float*)d_in[16];
    const float* rel_msg = (const float*)d_in[17];
    const float* rel_pri = (const float*)d_in[18];
    const float* skip = (const float*)d_in[19];

    char* w = (char*)d_ws;
    auto alloc = [&](size_t bytes) {
        char* p = w;
        w += (bytes + 255) & ~(size_t)255;
        return p;
    };
    // ws total ~165 MB (within known-good budget)
    unsigned short* WT  = (unsigned short*)alloc((size_t)10 * 65536 * 2);
    float* ball         = (float*)alloc((size_t)8 * 256 * 4);
    unsigned short* Qb  = (unsigned short*)alloc((size_t)2 * NS * 2);  // Q0,Q1 (bf16)
    unsigned short* Kb0 = (unsigned short*)alloc((size_t)NS * 2);      // K r0 (bf16)
    unsigned short* Kb1 = (unsigned short*)alloc((size_t)NS * 2);      // K r1 (bf16)
    unsigned short* Tb  = (unsigned short*)alloc((size_t)2 * NS * 2);  // t per type (bf16)
    int* offs           = (int*)alloc((size_t)3 * (NN + 1) * 4);
    int* srcS           = (int*)alloc((size_t)3 * EE * 4);
    int* bcnt           = (int*)alloc((size_t)3 * NBK * 4);
    int* bbase          = (int*)alloc((size_t)3 * (NBK + 1) * 4);
    int* bcur           = (int*)alloc((size_t)3 * NBK * 4);

    // 4 bf16 QKV slots live in d_out (102.4 MB, dead until final GEMM)
    unsigned short* dob = (unsigned short*)d_out;

    (void)hipMemsetAsync(bcnt, 0, (size_t)3 * NBK * 4, stream);

    // prep weights + P0 bucket histogram (fused; disjoint block ranges)
    setup_kernel<<<2568 + 3 * NT1, 256, 0, stream>>>(Wk, bk, Wq, bq, Wv, bv, Wa,
                                                     rel_att, rel_msg, WT, ball,
                                                     dst0, dst1, dst2, bcnt);
    bscan_kernel<<<3, 1024, 0, stream>>>(bcnt, bbase, bcur);
    p1_kernel<<<3 * NT1, 256, 0, stream>>>(src0, src1, src2, dst0, dst1, dst2,
                                           bcur, (unsigned int*)srcS);
    p2_kernel<<<3 * NBK, 256, 0, stream>>>(bbase, (unsigned int*)srcS, offs);

    // all 8 production GEMMs (Q0,Q1,K0,K1 in ws; K2,V0,V1,V2 in d_out)
    gemm8_kernel<<<dim3(391, 2, 8), 256, 0, stream>>>(hA, hB, WT, ball,
                                                      Qb, Kb0, Kb1, dob);

    // all 3 relations' aggregation in one launch
    agg_all_kernel<<<25000, 256, 0, stream>>>(Qb, Qb + NS, Kb0, dob + 1 * (size_t)NS,
                                              Kb1, dob + 2 * (size_t)NS,
                                              dob + 0 * (size_t)NS, dob + 3 * (size_t)NS,
                                              offs, srcS, rel_pri, Tb, Tb + NS);

    // output GEMM overwrites d_out (reads only Tb/hA/hB/WT)
    out_gemm_kernel<<<dim3(391, 2, 2), 256, 0, stream>>>(
        Tb, Tb + NS, WT + 8 * 65536, WT + 9 * 65536, ba, ba + 256,
        (float*)d_out, hA, hB, skip);
}